// Round 13
// baseline (515.512 us; speedup 1.0000x reference)
//
#include <hip/hip_runtime.h>
#include <math.h>

#define SS 256
#define BB 4
#define HH 256
#define LE 2994
#define LEB (LE*BB)
#define SCALE 0.08838834764831845f  // 1/sqrt(128)
#define QSTR 784   // qlds row stride: 784 % 32 == 16 -> 2-way (free) bank aliasing on 4x16 stores

typedef __attribute__((ext_vector_type(8))) short bf16x8;
typedef __attribute__((ext_vector_type(4))) float f32x4;

__device__ inline ushort f2b(float f) {   // fp32 -> bf16 RNE
    unsigned u = __float_as_uint(f);
    u += 0x7FFFu + ((u >> 16) & 1u);
    return (ushort)(u >> 16);
}

__device__ inline float qred(float x) {   // sum across 16 lanes of a quarter-wave (broadcast)
    x += __shfl_xor(x, 1); x += __shfl_xor(x, 2);
    x += __shfl_xor(x, 4); x += __shfl_xor(x, 8);
    return x;
}

// ---------------- init ----------------

__global__ void k_init(float* __restrict__ out, float* __restrict__ bnsums,
                       int* __restrict__ grp, int* __restrict__ idxt) {
    int bid = blockIdx.x, t = threadIdx.x;
    if (bid == 0) {
        if (t == 0) out[0] = 0.f;
        bnsums[t] = 0.f; bnsums[256 + t] = 0.f;
        return;
    }
    int e = (bid - 1) * 256 + t;
    if (e >= LE) return;
    int g, pos;
    if (e < 78) {
        g = (int)((1.0f + sqrtf(8.0f * (float)e + 1.0f)) * 0.5f);
        while (g * (g - 1) / 2 > e) g--;
        while ((g + 1) * g / 2 <= e) g++;
        pos = e - g * (g - 1) / 2;
        idxt[e] = pos;
    } else {
        int r = e - 78;
        g = 13 + r / 12;
        pos = r % 12;
        idxt[e] = g - 12 + pos;
    }
    grp[e] = g;
}

// ---------------- weight pre-pack ----------------

#define NPACK 14
#define TOTFRAG 2816
struct PackArgs { const float* src[NPACK]; int fs[NPACK + 1]; };

__global__ __launch_bounds__(256) void k_prep(PackArgs pa, ushort* __restrict__ dst) {
    int wid = (blockIdx.x * 256 + threadIdx.x) >> 6;
    int lane = threadIdx.x & 63;
    if (wid >= TOTFRAG) return;
    int i = 0;
    while (pa.fs[i + 1] <= wid) i++;
    int f = wid - pa.fs[i];
    int tn = f >> 3, tk = f & 7;
    int q = lane >> 4, p = lane & 15;
    const float* s = pa.src[i] + (size_t)(tn * 16 + p) * 256 + tk * 32 + q * 8;
    float4 a0 = *(const float4*)s, a1 = *(const float4*)(s + 4);
    uint4 o = make_uint4(f2b(a0.x) | ((unsigned)f2b(a0.y) << 16),
                         f2b(a0.z) | ((unsigned)f2b(a0.w) << 16),
                         f2b(a1.x) | ((unsigned)f2b(a1.y) << 16),
                         f2b(a1.z) | ((unsigned)f2b(a1.w) << 16));
    *(uint4*)&dst[(size_t)wid * 512 + lane * 8] = o;
}

// ---------------- plain bf16 GEMM with packed W (modes 0/3), 64-row x 256-col tiles ----------------

__global__ __launch_bounds__(256) void k_gemm_w(
    const float* __restrict__ A, const ushort* __restrict__ Wp,
    const float* __restrict__ bias, float* __restrict__ C, float* __restrict__ Vt,
    int M, int N, int mode, int relu)
{
    __shared__ ushort As[32 * 512];
    int tid = threadIdx.x;
    int w = tid >> 6, lane = tid & 63;
    int q = lane >> 4, p = lane & 15;
    int m0 = blockIdx.y * 64, n0 = blockIdx.x * 256;

    {
        int r = tid >> 2;
        int cbase = (tid & 3) * 64;
        int gm = m0 + r;
        const float* Ar = A + (size_t)gm * 256 + cbase;
        bool ok = gm < M;
        #pragma unroll
        for (int j = 0; j < 8; j++) {
            int c = cbase + j * 8;
            float4 a0, a1;
            if (ok) { a0 = *(const float4*)(Ar + j * 8); a1 = *(const float4*)(Ar + j * 8 + 4); }
            else { a0 = make_float4(0.f, 0.f, 0.f, 0.f); a1 = a0; }
            uint4 o = make_uint4(f2b(a0.x) | ((unsigned)f2b(a0.y) << 16),
                                 f2b(a0.z) | ((unsigned)f2b(a0.w) << 16),
                                 f2b(a1.x) | ((unsigned)f2b(a1.y) << 16),
                                 f2b(a1.z) | ((unsigned)f2b(a1.w) << 16));
            int frag = (r >> 4) * 8 + (c >> 5);
            int fl = ((c >> 3) & 3) * 16 + (r & 15);
            *(uint4*)&As[frag * 512 + fl * 8] = o;
        }
    }
    __syncthreads();

    f32x4 acc[4][4];
    #pragma unroll
    for (int i = 0; i < 4; i++)
        #pragma unroll
        for (int j = 0; j < 4; j++) acc[i][j] = (f32x4){0.f, 0.f, 0.f, 0.f};

    int nw = n0 + w * 64;
    const ushort* Wb = Wp + (size_t)(nw >> 4) * 4096;

    #pragma unroll
    for (int kt = 0; kt < 8; kt++) {
        bf16x8 afr[4], wfr[4];
        #pragma unroll
        for (int mt = 0; mt < 4; mt++)
            afr[mt] = *(const bf16x8*)&As[(mt * 8 + kt) * 512 + lane * 8];
        #pragma unroll
        for (int nt = 0; nt < 4; nt++)
            wfr[nt] = *(const bf16x8*)&Wb[(size_t)(nt * 8 + kt) * 512 + lane * 8];
        #pragma unroll
        for (int mt = 0; mt < 4; mt++)
            #pragma unroll
            for (int nt = 0; nt < 4; nt++)
                acc[mt][nt] = __builtin_amdgcn_mfma_f32_16x16x32_bf16(afr[mt], wfr[nt], acc[mt][nt], 0, 0, 0);
    }

    float bi[4]; int col[4];
    #pragma unroll
    for (int nt = 0; nt < 4; nt++) { col[nt] = nw + nt * 16 + p; bi[nt] = bias[col[nt]]; }
    #pragma unroll
    for (int mt = 0; mt < 4; mt++)
        #pragma unroll
        for (int reg = 0; reg < 4; reg++) {
            int grow = m0 + mt * 16 + q * 4 + reg;
            if (grow >= M) continue;
            #pragma unroll
            for (int nt = 0; nt < 4; nt++) {
                float v = acc[mt][nt][reg] + bi[nt];
                if (relu) v = fmaxf(v, 0.f);
                if (mode == 3) {
                    if (col[nt] < 512) {
                        C[(size_t)grow * 768 + col[nt]] = v;
                    } else {
                        int hh = (col[nt] - 512) >> 7, dh = (col[nt] - 512) & 127;
                        int zz = (grow & 3) * 2 + hh;
                        Vt[(size_t)zz * 32768 + (size_t)dh * 256 + (grow >> 2)] = v;
                    }
                } else {
                    C[(size_t)grow * N + col[nt]] = v;
                }
            }
        }
}

// ---------------- 16-row / 4-wave pipeline building blocks ----------------

__device__ inline void stageA_16(const float* __restrict__ A, int M, int m0, int tid,
                                 ushort* __restrict__ As) {
    int r = tid >> 4;
    int cbase = (tid & 15) * 16;
    int gm = m0 + r;
    const float* Ar = A + (size_t)gm * 256 + cbase;
    bool ok = gm < M;
    #pragma unroll
    for (int j = 0; j < 2; j++) {
        int c = cbase + j * 8;
        float4 a0, a1;
        if (ok) { a0 = *(const float4*)(Ar + j * 8); a1 = *(const float4*)(Ar + j * 8 + 4); }
        else { a0 = make_float4(0.f, 0.f, 0.f, 0.f); a1 = a0; }
        uint4 o = make_uint4(f2b(a0.x) | ((unsigned)f2b(a0.y) << 16),
                             f2b(a0.z) | ((unsigned)f2b(a0.w) << 16),
                             f2b(a1.x) | ((unsigned)f2b(a1.y) << 16),
                             f2b(a1.z) | ((unsigned)f2b(a1.w) << 16));
        int frag = c >> 5;
        int fl = ((c >> 3) & 3) * 16 + r;
        *(uint4*)&As[frag * 512 + fl * 8] = o;
    }
    __syncthreads();
}

__device__ inline void gemm_pass16(const ushort* __restrict__ As, const ushort* __restrict__ Wq,
                                   int w, int lane, f32x4 (&acc)[4]) {
    #pragma unroll
    for (int nt = 0; nt < 4; nt++) acc[nt] = (f32x4){0.f, 0.f, 0.f, 0.f};
    #pragma unroll
    for (int kt = 0; kt < 8; kt++) {
        bf16x8 a0 = *(const bf16x8*)&As[kt * 512 + lane * 8];
        #pragma unroll
        for (int nt = 0; nt < 4; nt++) {
            bf16x8 wf = *(const bf16x8*)&Wq[(size_t)((w * 4 + nt) * 8 + kt) * 512 + lane * 8];
            acc[nt] = __builtin_amdgcn_mfma_f32_16x16x32_bf16(a0, wf, acc[nt], 0, 0, 0);
        }
    }
}

__device__ inline void stage_acc16(const f32x4 (&acc)[4], ushort* __restrict__ As,
                                   int w, int q, int p) {
    __syncthreads();
    #pragma unroll
    for (int nt = 0; nt < 4; nt++)
        #pragma unroll
        for (int reg = 0; reg < 4; reg++)
            As[(w * 2 + (nt >> 1)) * 512 +
               (((nt * 2 + (p >> 3)) & 3) * 16 + q * 4 + reg) * 8 + (p & 7)] =
                f2b(acc[nt][reg]);
    __syncthreads();
}

__device__ inline void block_ln16(f32x4 (&acc)[4], float* __restrict__ red,
                                  int tid, int w, int q, int p,
                                  const float* __restrict__ g, const float* __restrict__ b) {
    float gg[4], bb[4];
    #pragma unroll
    for (int nt = 0; nt < 4; nt++) { int col = w * 64 + nt * 16 + p; gg[nt] = g[col]; bb[nt] = b[col]; }
    #pragma unroll
    for (int reg = 0; reg < 4; reg++) {
        float s = acc[0][reg] + acc[1][reg] + acc[2][reg] + acc[3][reg];
        s = qred(s);
        if (p == 0) red[w * 16 + q * 4 + reg] = s;
    }
    __syncthreads();
    if (tid < 16) red[64 + tid] = (red[tid] + red[16 + tid] + red[32 + tid] + red[48 + tid]) * (1.f / 256.f);
    __syncthreads();
    #pragma unroll
    for (int reg = 0; reg < 4; reg++) {
        int lr = q * 4 + reg;
        float mean = red[64 + lr];
        float sq = 0.f;
        #pragma unroll
        for (int nt = 0; nt < 4; nt++) {
            acc[nt][reg] -= mean;
            sq += acc[nt][reg] * acc[nt][reg];
        }
        sq = qred(sq);
        if (p == 0) red[w * 16 + lr] = sq;
    }
    __syncthreads();
    if (tid < 16) red[64 + tid] = rsqrtf((red[tid] + red[16 + tid] + red[32 + tid] + red[48 + tid]) * (1.f / 256.f) + 1e-5f);
    __syncthreads();
    #pragma unroll
    for (int reg = 0; reg < 4; reg++) {
        float rstd = red[64 + q * 4 + reg];
        #pragma unroll
        for (int nt = 0; nt < 4; nt++)
            acc[nt][reg] = acc[nt][reg] * rstd * gg[nt] + bb[nt];
    }
    __syncthreads();
}

// ---------------- node mega: so+LN, +crO+LN, ff1, ff2+LN(+final LN) — 16 rows/block ----------------

__global__ __launch_bounds__(256) void k_node_mega(
    const float* __restrict__ t1, const float* __restrict__ tgt,
    const float* __restrict__ crO,
    const ushort* __restrict__ Wso, const float* __restrict__ so_b,
    const float* __restrict__ ln0g, const float* __restrict__ ln0b,
    const float* __restrict__ ln1g, const float* __restrict__ ln1b,
    const ushort* __restrict__ Wff1, const float* __restrict__ ff1_b,
    const ushort* __restrict__ Wff2, const float* __restrict__ ff2_b,
    const float* __restrict__ ln2g, const float* __restrict__ ln2b,
    const float* __restrict__ fng, const float* __restrict__ fnb,
    float* __restrict__ outp, int M, int finalln)
{
    __shared__ ushort As[8 * 512];
    __shared__ float red[128];
    int tid = threadIdx.x;
    int w = tid >> 6, lane = tid & 63, q = lane >> 4, p = lane & 15;
    int m0 = blockIdx.x * 16;

    float x[4][4];
    f32x4 acc[4];

    stageA_16(t1, M, m0, tid, As);
    #pragma unroll
    for (int reg = 0; reg < 4; reg++) {
        int row = m0 + q * 4 + reg;
        bool ok = row < M;
        #pragma unroll
        for (int nt = 0; nt < 4; nt++)
            x[nt][reg] = ok ? tgt[(size_t)row * 256 + w * 64 + nt * 16 + p] : 0.f;
    }

    gemm_pass16(As, Wso, w, lane, acc);
    {
        float bi[4];
        #pragma unroll
        for (int nt = 0; nt < 4; nt++) bi[nt] = so_b[w * 64 + nt * 16 + p];
        #pragma unroll
        for (int nt = 0; nt < 4; nt++)
            #pragma unroll
            for (int reg = 0; reg < 4; reg++)
                acc[nt][reg] += bi[nt] + x[nt][reg];
    }
    block_ln16(acc, red, tid, w, q, p, ln0g, ln0b);

    #pragma unroll
    for (int reg = 0; reg < 4; reg++) {
        int row = m0 + q * 4 + reg;
        int b = row & 3;
        #pragma unroll
        for (int nt = 0; nt < 4; nt++)
            acc[nt][reg] += crO[b * 256 + w * 64 + nt * 16 + p];
    }
    block_ln16(acc, red, tid, w, q, p, ln1g, ln1b);

    #pragma unroll
    for (int nt = 0; nt < 4; nt++)
        #pragma unroll
        for (int reg = 0; reg < 4; reg++)
            x[nt][reg] = acc[nt][reg];

    stage_acc16(acc, As, w, q, p);
    gemm_pass16(As, Wff1, w, lane, acc);
    {
        float bi[4];
        #pragma unroll
        for (int nt = 0; nt < 4; nt++) bi[nt] = ff1_b[w * 64 + nt * 16 + p];
        #pragma unroll
        for (int nt = 0; nt < 4; nt++)
            #pragma unroll
            for (int reg = 0; reg < 4; reg++)
                acc[nt][reg] = fmaxf(acc[nt][reg] + bi[nt], 0.f);
    }

    stage_acc16(acc, As, w, q, p);
    gemm_pass16(As, Wff2, w, lane, acc);
    {
        float bi[4];
        #pragma unroll
        for (int nt = 0; nt < 4; nt++) bi[nt] = ff2_b[w * 64 + nt * 16 + p];
        #pragma unroll
        for (int nt = 0; nt < 4; nt++)
            #pragma unroll
            for (int reg = 0; reg < 4; reg++)
                acc[nt][reg] += bi[nt] + x[nt][reg];
    }
    block_ln16(acc, red, tid, w, q, p, ln2g, ln2b);
    if (finalln) block_ln16(acc, red, tid, w, q, p, fng, fnb);

    #pragma unroll
    for (int reg = 0; reg < 4; reg++) {
        int row = m0 + q * 4 + reg;
        if (row >= M) continue;
        #pragma unroll
        for (int nt = 0; nt < 4; nt++)
            outp[(size_t)row * 256 + w * 64 + nt * 16 + p] = acc[nt][reg];
    }
}

// ---------------- edge mega (16 rows/block) ----------------

__global__ __launch_bounds__(256) void k_edge_mega(
    const float* __restrict__ et1, const float* __restrict__ etgt,
    const ushort* __restrict__ Wso, const float* __restrict__ so_b,
    const float* __restrict__ ln0g, const float* __restrict__ ln0b,
    const ushort* __restrict__ Wcq, const float* __restrict__ cq_b,
    const float* __restrict__ KV, const int* __restrict__ grp,
    const ushort* __restrict__ Wco, const float* __restrict__ co_b,
    const float* __restrict__ ln1g, const float* __restrict__ ln1b,
    const ushort* __restrict__ Wff1, const float* __restrict__ ff1_b,
    const ushort* __restrict__ Wff2, const float* __restrict__ ff2_b,
    const float* __restrict__ ln2g, const float* __restrict__ ln2b,
    const float* __restrict__ fng, const float* __restrict__ fnb,
    const int* __restrict__ ydata,
    const float* __restrict__ cw0, const float* __restrict__ cb0,
    const float* __restrict__ cw1, const float* __restrict__ cb1,
    float* __restrict__ lossOut, float invM, int M)
{
    __shared__ ushort As[8 * 512];
    __shared__ float red[640];
    int tid = threadIdx.x;
    int w = tid >> 6, lane = tid & 63, q = lane >> 4, p = lane & 15;
    int m0 = blockIdx.x * 16;

    float x[4][4];
    f32x4 acc[4];

    stageA_16(et1, M, m0, tid, As);
    #pragma unroll
    for (int reg = 0; reg < 4; reg++) {
        int row = m0 + q * 4 + reg;
        bool ok = row < M;
        #pragma unroll
        for (int nt = 0; nt < 4; nt++)
            x[nt][reg] = ok ? etgt[(size_t)row * 256 + w * 64 + nt * 16 + p] : 0.f;
    }

    gemm_pass16(As, Wso, w, lane, acc);
    {
        float bi[4];
        #pragma unroll
        for (int nt = 0; nt < 4; nt++) bi[nt] = so_b[w * 64 + nt * 16 + p];
        #pragma unroll
        for (int nt = 0; nt < 4; nt++)
            #pragma unroll
            for (int reg = 0; reg < 4; reg++)
                acc[nt][reg] += bi[nt] + x[nt][reg];
    }
    block_ln16(acc, red, tid, w, q, p, ln0g, ln0b);
    #pragma unroll
    for (int nt = 0; nt < 4; nt++)
        #pragma unroll
        for (int reg = 0; reg < 4; reg++)
            x[nt][reg] = acc[nt][reg];

    stage_acc16(acc, As, w, q, p);
    gemm_pass16(As, Wcq, w, lane, acc);
    {
        int h = w >> 1;
        float bi[4];
        #pragma unroll
        for (int nt = 0; nt < 4; nt++) bi[nt] = cq_b[w * 64 + nt * 16 + p];
        #pragma unroll
        for (int reg = 0; reg < 4; reg++) {
            int lr = q * 4 + reg;
            int row = m0 + lr;
            bool ok = row < M;
            int b = row & 3;
            int g = ok ? grp[row >> 2] : 0;
            const float* K0 = KV + (size_t)b * 512 + h * 128;
            const float* K1 = KV + ((size_t)(g + 1) * 4 + b) * 512 + h * 128;
            float s0 = 0.f, s1 = 0.f;
            #pragma unroll
            for (int nt = 0; nt < 4; nt++) {
                float qv = acc[nt][reg] + bi[nt];
                int d = (w & 1) * 64 + nt * 16 + p;
                s0 += qv * K0[d]; s1 += qv * K1[d];
            }
            s0 = qred(s0); s1 = qred(s1);
            if (p == 0) { red[(w * 16 + lr) * 2 + 0] = s0; red[(w * 16 + lr) * 2 + 1] = s1; }
        }
        __syncthreads();
        if (tid < 32) {
            int hh = tid >> 4, lr = tid & 15;
            float p0 = (red[((hh * 2) * 16 + lr) * 2 + 0] + red[((hh * 2 + 1) * 16 + lr) * 2 + 0]) * SCALE;
            float p1 = (red[((hh * 2) * 16 + lr) * 2 + 1] + red[((hh * 2 + 1) * 16 + lr) * 2 + 1]) * SCALE;
            float mx = fmaxf(p0, p1);
            float e0 = __expf(p0 - mx), e1 = __expf(p1 - mx);
            float inv = 1.f / (e0 + e1);
            red[128 + (hh * 16 + lr) * 2 + 0] = e0 * inv;
            red[128 + (hh * 16 + lr) * 2 + 1] = e1 * inv;
        }
        __syncthreads();
        #pragma unroll
        for (int reg = 0; reg < 4; reg++) {
            int lr = q * 4 + reg;
            int row = m0 + lr;
            bool ok = row < M;
            int b = row & 3;
            int g = ok ? grp[row >> 2] : 0;
            float e0 = red[128 + (h * 16 + lr) * 2 + 0];
            float e1 = red[128 + (h * 16 + lr) * 2 + 1];
            const float* V0 = KV + (size_t)b * 512 + 256 + h * 128;
            const float* V1 = KV + ((size_t)(g + 1) * 4 + b) * 512 + 256 + h * 128;
            #pragma unroll
            for (int nt = 0; nt < 4; nt++) {
                int d = (w & 1) * 64 + nt * 16 + p;
                acc[nt][reg] = e0 * V0[d] + e1 * V1[d];
            }
        }
        __syncthreads();
    }

    stage_acc16(acc, As, w, q, p);
    gemm_pass16(As, Wco, w, lane, acc);
    {
        float bi[4];
        #pragma unroll
        for (int nt = 0; nt < 4; nt++) bi[nt] = co_b[w * 64 + nt * 16 + p];
        #pragma unroll
        for (int nt = 0; nt < 4; nt++)
            #pragma unroll
            for (int reg = 0; reg < 4; reg++)
                acc[nt][reg] += bi[nt] + x[nt][reg];
    }
    block_ln16(acc, red, tid, w, q, p, ln1g, ln1b);
    #pragma unroll
    for (int nt = 0; nt < 4; nt++)
        #pragma unroll
        for (int reg = 0; reg < 4; reg++)
            x[nt][reg] = acc[nt][reg];

    stage_acc16(acc, As, w, q, p);
    gemm_pass16(As, Wff1, w, lane, acc);
    {
        float bi[4];
        #pragma unroll
        for (int nt = 0; nt < 4; nt++) bi[nt] = ff1_b[w * 64 + nt * 16 + p];
        #pragma unroll
        for (int nt = 0; nt < 4; nt++)
            #pragma unroll
            for (int reg = 0; reg < 4; reg++)
                acc[nt][reg] = fmaxf(acc[nt][reg] + bi[nt], 0.f);
    }

    stage_acc16(acc, As, w, q, p);
    gemm_pass16(As, Wff2, w, lane, acc);
    {
        float bi[4];
        #pragma unroll
        for (int nt = 0; nt < 4; nt++) bi[nt] = ff2_b[w * 64 + nt * 16 + p];
        #pragma unroll
        for (int nt = 0; nt < 4; nt++)
            #pragma unroll
            for (int reg = 0; reg < 4; reg++)
                acc[nt][reg] += bi[nt] + x[nt][reg];
    }
    block_ln16(acc, red, tid, w, q, p, ln2g, ln2b);
    block_ln16(acc, red, tid, w, q, p, fng, fnb);

    #pragma unroll
    for (int c = 0; c < 9; c++) {
        const float* wc = (c < 5) ? (cw0 + (size_t)c * 256) : (cw1 + (size_t)(c - 5) * 256);
        float wv[4];
        #pragma unroll
        for (int nt = 0; nt < 4; nt++) wv[nt] = wc[w * 64 + nt * 16 + p];
        #pragma unroll
        for (int reg = 0; reg < 4; reg++) {
            float s = acc[0][reg] * wv[0] + acc[1][reg] * wv[1]
                    + acc[2][reg] * wv[2] + acc[3][reg] * wv[3];
            s = qred(s);
            if (p == 0) red[(c * 4 + w) * 16 + q * 4 + reg] = s;
        }
    }
    __syncthreads();
    if (tid < 16) {
        float local = 0.f;
        int grow = m0 + tid;
        if (grow < M) {
            int y0 = ydata[(size_t)grow * 2 + 0], y1 = ydata[(size_t)grow * 2 + 1];
            float lg[9];
            #pragma unroll
            for (int c = 0; c < 9; c++)
                lg[c] = red[(c * 4 + 0) * 16 + tid] + red[(c * 4 + 1) * 16 + tid]
                      + red[(c * 4 + 2) * 16 + tid] + red[(c * 4 + 3) * 16 + tid]
                      + ((c < 5) ? cb0[c] : cb1[c - 5]);
            float mA = -1e30f, mB = -1e30f, tA = 0.f, tB = 0.f;
            #pragma unroll
            for (int c = 0; c < 5; c++) { mA = fmaxf(mA, lg[c]); if (c == y0) tA = lg[c]; }
            #pragma unroll
            for (int c = 0; c < 4; c++) { mB = fmaxf(mB, lg[5 + c]); if (c == y1) tB = lg[5 + c]; }
            float sA = 0.f, sB = 0.f;
            #pragma unroll
            for (int c = 0; c < 5; c++) sA += __expf(lg[c] - mA);
            #pragma unroll
            for (int c = 0; c < 4; c++) sB += __expf(lg[5 + c] - mB);
            local = (mA + logf(sA) - tA) + (mB + logf(sB) - tB);
        }
        for (int o = 8; o; o >>= 1) local += __shfl_down(local, o);
        if (tid == 0) atomicAdd(lossOut, local * invM);
    }
}

// ---------------- fused node attention: QK^T + softmax + PV in one kernel ----------------

__global__ __launch_bounds__(256) void k_attn_fused(
    const float* __restrict__ qkv, const float* __restrict__ Vt,
    float* __restrict__ outp)
{
    __shared__ ushort Qs[64 * 32];
    __shared__ ushort Ks[256 * 32];
    __shared__ ushort Pl[32 * 512];
    int tid = threadIdx.x;
    int wave = tid >> 6, lane = tid & 63;
    int q = lane >> 4, p = lane & 15;
    int m0 = blockIdx.x * 64;
    int z = blockIdx.y, b = z >> 1, h = z & 1;
    size_t qoff = (size_t)b * 768 + h * 128;

    f32x4 acc[16];
    #pragma unroll
    for (int i = 0; i < 16; i++) acc[i] = (f32x4){0.f, 0.f, 0.f, 0.f};

    int sra = tid >> 2, sca = (tid & 3) << 3;
    const float* Arow = qkv + (size_t)(m0 + sra) * 3072 + qoff + sca;
    const float* Wrow = qkv + (size_t)tid * 3072 + qoff + 256;
    ushort* asd = &Qs[sra * 32 + sca];
    ushort* wsd = &Ks[tid * 32];

    for (int k0 = 0; k0 < 128; k0 += 32) {
        float4 a0 = *(const float4*)(Arow + k0);
        float4 a1 = *(const float4*)(Arow + k0 + 4);
        float av[8] = {a0.x, a0.y, a0.z, a0.w, a1.x, a1.y, a1.z, a1.w};
        float wv[32];
        #pragma unroll
        for (int i = 0; i < 8; i++) {
            float4 w4 = *(const float4*)(Wrow + k0 + i * 4);
            wv[i*4+0] = w4.x; wv[i*4+1] = w4.y; wv[i*4+2] = w4.z; wv[i*4+3] = w4.w;
        }
        unsigned au[4], wu[16];
        #pragma unroll
        for (int i = 0; i < 4; i++) au[i] = (unsigned)f2b(av[2*i]) | ((unsigned)f2b(av[2*i+1]) << 16);
        #pragma unroll
        for (int i = 0; i < 16; i++) wu[i] = (unsigned)f2b(wv[2*i]) | ((unsigned)f2b(wv[2*i+1]) << 16);
        __syncthreads();
        ((uint4*)asd)[0] = make_uint4(au[0], au[1], au[2], au[3]);
        ((uint4*)wsd)[0] = make_uint4(wu[0], wu[1], wu[2], wu[3]);
        ((uint4*)(wsd + 8))[0] = make_uint4(wu[4], wu[5], wu[6], wu[7]);
        ((uint4*)(wsd + 16))[0] = make_uint4(wu[8], wu[9], wu[10], wu[11]);
        ((uint4*)(wsd + 24))[0] = make_uint4(wu[12], wu[13], wu[14], wu[15]);
        __syncthreads();

        bf16x8 af = *(const bf16x8*)&Qs[(wave * 16 + p) * 32 + q * 8];
        #pragma unroll
        for (int nt = 0; nt < 16; nt++) {
            bf16x8 bf = *(const bf16x8*)&Ks[(nt * 16 + p) * 32 + q * 8];
            acc[nt] = __builtin_amdgcn_mfma_f32_16x16x32_bf16(af, bf, acc[nt], 0, 0, 0);
        }
    }

    #pragma unroll
    for (int reg = 0; reg < 4; reg++) {
        int row = m0 + wave * 16 + q * 4 + reg;
        float v[16]; float mx = -1e30f;
        #pragma unroll
        for (int nt = 0; nt < 16; nt++) {
            int colk = nt * 16 + p;
            float val = (colk <= row) ? acc[nt][reg] * SCALE : -1e30f;
            v[nt] = val; mx = fmaxf(mx, val);
        }
        mx = fmaxf(mx, __shfl_xor(mx, 1)); mx = fmaxf(mx, __shfl_xor(mx, 2));
        mx = fmaxf(mx, __shfl_xor(mx, 4)); mx = fmaxf(mx, __shfl_xor(mx, 8));
        float s = 0.f;
        #pragma unroll
        for (int nt = 0; nt < 16; nt++) {
            int colk = nt * 16 + p;
            float e = (colk <= row) ? __expf(v[nt] - mx) : 0.f;
            v[nt] = e; s += e;
        }
        s += __shfl_xor(s, 1); s += __shfl_xor(s, 2); s += __shfl_xor(s, 4); s += __shfl_xor(s, 8);
        float inv = 1.f / s;
        #pragma unroll
        for (int nt = 0; nt < 16; nt++)
            Pl[(wave * 8 + (nt >> 1)) * 512 +
               ((((nt * 2) + (p >> 3)) & 3) * 16 + q * 4 + reg) * 8 + (p & 7)] = f2b(v[nt] * inv);
    }

    f32x4 a2[8];
    #pragma unroll
    for (int i = 0; i < 8; i++) a2[i] = (f32x4){0.f, 0.f, 0.f, 0.f};
    #pragma unroll
    for (int kt = 0; kt < 8; kt++) {
        bf16x8 af = *(const bf16x8*)&Pl[(wave * 8 + kt) * 512 + lane * 8];
        #pragma unroll
        for (int nt = 0; nt < 8; nt++) {
            const float* vr = Vt + (size_t)z * 32768 + (size_t)(nt * 16 + p) * 256 + kt * 32 + q * 8;
            float4 v0 = *(const float4*)vr;
            float4 v1 = *(const float4*)(vr + 4);
            uint4 wu = make_uint4(f2b(v0.x) | ((unsigned)f2b(v0.y) << 16),
                                  f2b(v0.z) | ((unsigned)f2b(v0.w) << 16),
                                  f2b(v1.x) | ((unsigned)f2b(v1.y) << 16),
                                  f2b(v1.z) | ((unsigned)f2b(v1.w) << 16));
            bf16x8 bf = *(bf16x8*)&wu;
            a2[nt] = __builtin_amdgcn_mfma_f32_16x16x32_bf16(af, bf, a2[nt], 0, 0, 0);
        }
    }
    #pragma unroll
    for (int reg = 0; reg < 4; reg++) {
        int row = m0 + wave * 16 + q * 4 + reg;
        #pragma unroll
        for (int nt = 0; nt < 8; nt++)
            outp[(size_t)row * 1024 + (size_t)b * 256 + h * 128 + nt * 16 + p] = a2[nt][reg];
    }
}

// ---------------- fused edge QKV + group self-attention (block per (g,b)) ----------------
// qlds row stride QSTR=784 (== 16 mod 32) -> 4x16 store tile = 2 lanes/bank (free).

__global__ __launch_bounds__(256) void k_edge_qkv_attn(
    const float* __restrict__ etgt, const ushort* __restrict__ Wq,
    const float* __restrict__ bias, float* __restrict__ et1)
{
    __shared__ ushort As[8 * 512];
    __shared__ float qlds[12 * QSTR];
    __shared__ float ps[2][12][12];
    int tid = threadIdx.x;
    int w = tid >> 6, lane = tid & 63, q = lane >> 4, p = lane & 15;
    int g = blockIdx.x + 1;
    int b = blockIdx.y;
    int gs = min(g, 12);
    int base = (g <= 13) ? g * (g - 1) / 2 : 78 + (g - 13) * 12;

    {
        int r = tid >> 4;
        int cbase = (tid & 15) * 16;
        bool ok = r < gs;
        const float* Ar = etgt + ((size_t)(base + r) * 4 + b) * 256 + cbase;
        #pragma unroll
        for (int j = 0; j < 2; j++) {
            int c = cbase + j * 8;
            float4 a0, a1;
            if (ok) { a0 = *(const float4*)(Ar + j * 8); a1 = *(const float4*)(Ar + j * 8 + 4); }
            else { a0 = make_float4(0.f, 0.f, 0.f, 0.f); a1 = a0; }
            uint4 o = make_uint4(f2b(a0.x) | ((unsigned)f2b(a0.y) << 16),
                                 f2b(a0.z) | ((unsigned)f2b(a0.w) << 16),
                                 f2b(a1.x) | ((unsigned)f2b(a1.y) << 16),
                                 f2b(a1.z) | ((unsigned)f2b(a1.w) << 16));
            *(uint4*)&As[(c >> 5) * 512 + (((c >> 3) & 3) * 16 + r) * 8] = o;
        }
    }
    __syncthreads();

    f32x4 acc[12];
    #pragma unroll
    for (int j = 0; j < 12; j++) acc[j] = (f32x4){0.f, 0.f, 0.f, 0.f};
    #pragma unroll
    for (int kt = 0; kt < 8; kt++) {
        bf16x8 af = *(const bf16x8*)&As[kt * 512 + lane * 8];
        #pragma unroll
        for (int j = 0; j < 12; j++) {
            bf16x8 wf = *(const bf16x8*)&Wq[(size_t)((w * 12 + j) * 8 + kt) * 512 + lane * 8];
            acc[j] = __builtin_amdgcn_mfma_f32_16x16x32_bf16(af, wf, acc[j], 0, 0, 0);
        }
    }
    #pragma unroll
    for (int j = 0; j < 12; j++) {
        int col = (w * 12 + j) * 16 + p;
        float bi = bias[col];
        #pragma unroll
        for (int reg = 0; reg < 4; reg++) {
            int row = q * 4 + reg;
            if (row < 12) qlds[row * QSTR + col] = acc[j][reg] + bi;
        }
    }
    __syncthreads();

    int h = tid >> 7, t = tid & 127;
    for (int pidx = t; pidx < gs * gs; pidx += 128) {
        int i = pidx / gs, jj = pidx - i * gs;
        const float* qp = &qlds[i * QSTR + h * 128];
        const float* kp = &qlds[jj * QSTR + 256 + h * 128];
        float a = 0.f;
        for (int d = 0; d < 128; d++) a = fmaf(qp[d], kp[d], a);
        ps[h][i][jj] = a * SCALE;
    }
    __syncthreads();
    if (t < gs) {
        float m = -1e30f;
        for (int jj = 0; jj < gs; jj++) m = fmaxf(m, ps[h][t][jj]);
        float e[12]; float s = 0.f;
        for (int jj = 0; jj < gs; jj++) { e[jj] = __expf(ps[h][t][jj] - m); s += e[jj]; }
        float inv = 1.f / s;
        for (int jj = 0; jj < gs; jj++) ps[h][t][jj] = e[jj] * inv;
    }
    __syncthreads();
    for (int i = 0; i < gs; i++) {
        float a = 0.f;
        for (int jj = 0; jj < gs; jj++) a = fmaf(ps[h][i][jj], qlds[jj * QSTR + 512 + h * 128 + t], a);
        et1[((size_t)(base + i) * 4 + b) * 256 + h * 128 + t] = a;
    }
}

// ---------------- generic fp32 GEMM (input projection K=54 only) ----------------

__global__ __launch_bounds__(256) void k_gemm(
    const float* __restrict__ A, const float* __restrict__ W,
    const float* __restrict__ bias, float* __restrict__ C,
    int M, int N, int K, int relu)
{
    __shared__ __align__(16) float As[16][68];
    __shared__ __align__(16) float Ws[16][68];
    int tx = threadIdx.x, ty = threadIdx.y;
    int tid = ty * 16 + tx;
    int m0 = blockIdx.y * 64, n0 = blockIdx.x * 64;
    float acc[4][4] = {{0.f}};
    int r  = tid >> 2;
    int kk = (tid & 3) << 2;
    for (int k0 = 0; k0 < K; k0 += 16) {
        float4 av = make_float4(0.f, 0.f, 0.f, 0.f);
        float4 wv = make_float4(0.f, 0.f, 0.f, 0.f);
        int gm = m0 + r, gk = k0 + kk;
        if (gm < M) {
            float tv[4];
            for (int i = 0; i < 4; i++) tv[i] = (gk + i < K) ? A[(size_t)gm * K + gk + i] : 0.f;
            av = make_float4(tv[0], tv[1], tv[2], tv[3]);
        }
        int gn = n0 + r;
        if (gn < N) {
            float tv[4];
            for (int i = 0; i < 4; i++) tv[i] = (gk + i < K) ? W[(size_t)gn * K + gk + i] : 0.f;
            wv = make_float4(tv[0], tv[1], tv[2], tv[3]);
        }
        As[kk + 0][r] = av.x; As[kk + 1][r] = av.y; As[kk + 2][r] = av.z; As[kk + 3][r] = av.w;
        Ws[kk + 0][r] = wv.x; Ws[kk + 1][r] = wv.y; Ws[kk + 2][r] = wv.z; Ws[kk + 3][r] = wv.w;
        __syncthreads();
        #pragma unroll
        for (int k = 0; k < 16; k++) {
            float4 a4 = *(const float4*)&As[k][ty << 2];
            float4 b4 = *(const float4*)&Ws[k][tx << 2];
            float a[4] = {a4.x, a4.y, a4.z, a4.w};
            float b[4] = {b4.x, b4.y, b4.z, b4.w};
            #pragma unroll
            for (int i = 0; i < 4; i++)
                #pragma unroll
                for (int j = 0; j < 4; j++)
                    acc[i][j] = fmaf(a[i], b[j], acc[i][j]);
        }
        __syncthreads();
    }
    #pragma unroll
    for (int i = 0; i < 4; i++) {
        int gm = m0 + (ty << 2) + i;
        if (gm >= M) continue;
        #pragma unroll
        for (int j = 0; j < 4; j++) {
            int gn = n0 + (tx << 2) + j;
            if (gn >= N) continue;
            float v = acc[i][j] + bias[gn];
            if (relu) v = fmaxf(v, 0.f);
            C[(size_t)gm * N + gn] = v;
        }
    }
}

// ---------------- BatchNorm partial sums ----------------

__global__ __launch_bounds__(256) void k_bn_part(const float* __restrict__ x, float* __restrict__ sums) {
    int t = threadIdx.x;
    int r0 = blockIdx.x * 16;
    float s = 0.f, s2 = 0.f;
    for (int r = r0; r < r0 + 16; r++) {
        float v = x[(size_t)r * 256 + t];
        s += v; s2 += v * v;
    }
    atomicAdd(&sums[t], s);
    atomicAdd(&sums[256 + t], s2);
}

// ---------------- BN-finalize + SELU + positional encoding ----------------

__global__ __launch_bounds__(256) void k_bn_selu_pe(
    const float* __restrict__ x0, const float* __restrict__ sums,
    const float* __restrict__ g, const float* __restrict__ b,
    const int* __restrict__ atom_i, float* __restrict__ out)
{
    int row = blockIdx.x, t = threadIdx.x;
    float m = sums[t] * (1.f / 1024.f);
    float var = sums[256 + t] * (1.f / 1024.f) - m * m;
    float rstd = rsqrtf(var + 1e-5f);
    float v = x0[(size_t)row * 256 + t];
    v = (v - m) * rstd * g[t] + b[t];
    const float SC = 1.0507009873554805f, AL = 1.6732632423543772f;
    v = SC * (v > 0.f ? v : AL * expm1f(v));
    float pos = (float)atom_i[row];
    float freq = expf(-(float)t * (9.210340371976184f / 256.f));
    float ang = pos * freq;
    float pe = (t & 1) ? cosf(ang) : sinf(ang);
    out[(size_t)row * 256 + t] = v + pe;
}

// ---------------- both-layer node cross-attn constant ----------------

__global__ __launch_bounds__(256) void k_cross2(
    const float* __restrict__ z, const float* __restrict__ cqkv_w, const float* __restrict__ cqkv_b,
    const float* __restrict__ co_w, const float* __restrict__ co_b, float* __restrict__ crO)
{
    int m = blockIdx.x, l = blockIdx.y;
    int t = threadIdx.x;
    __shared__ float zs[256], ct[256];
    zs[t] = z[m * 256 + t];
    __syncthreads();
    const float* wv = cqkv_w + (size_t)l * 768 * 256 + 512 * 256 + (size_t)t * 256;
    float a = cqkv_b[l * 768 + 512 + t];
    for (int d = 0; d < 256; d += 4) {
        float4 w4 = *(const float4*)(wv + d);
        a += zs[d] * w4.x + zs[d+1] * w4.y + zs[d+2] * w4.z + zs[d+3] * w4.w;
    }
    ct[t] = a;
    __syncthreads();
    const float* ow = co_w + (size_t)l * 65536 + (size_t)t * 256;
    float o = co_b[l * 256 + t];
    for (int d = 0; d < 256; d += 4) {
        float4 w4 = *(const float4*)(ow + d);
        o += ct[d] * w4.x + ct[d+1] * w4.y + ct[d+2] * w4.z + ct[d+3] * w4.w;
    }
    crO[l * 1024 + m * 256 + t] = o;
}

// ---------------- gather + build_mem fused ----------------

__global__ __launch_bounds__(256) void k_gather_mem(
    const float* __restrict__ z, const float* __restrict__ nemb,
    const int* __restrict__ idxt, float* __restrict__ etgt, float* __restrict__ memb)
{
    int r = blockIdx.x, t = threadIdx.x;
    if (r < LEB) {
        int e = r >> 2, b = r & 3;
        etgt[(size_t)r * 256 + t] = nemb[((size_t)idxt[e] * 4 + b) * 256 + t];
    } else {
        int rm = r - LEB;
        int m = rm >> 2, b = rm & 3;
        memb[(size_t)rm * 256 + t] = (m == 0) ? z[(size_t)b * 256 + t]
                                              : nemb[((size_t)(m - 1) * 4 + b) * 256 + t];
    }
}

// ---------------- fused node cross-entropy ----------------

__global__ __launch_bounds__(256) void k_ce_node(
    const float* __restrict__ emb,
    const float* __restrict__ w0, const float* __restrict__ b0,
    const float* __restrict__ w1, const float* __restrict__ b1,
    const float* __restrict__ w2, const float* __restrict__ b2,
    const int* __restrict__ y, int M, float invM, float* __restrict__ lossOut)
{
    int wave = threadIdx.x >> 6, lane = threadIdx.x & 63;
    int wid = blockIdx.x * 4 + wave;
    float local = 0.f;
    for (int r = wid; r < M; r += gridDim.x * 4) {
        float4 x = ((const float4*)(emb + (size_t)r * 256))[lane];
        float acc[54];
        #pragma unroll
        for (int c = 0; c < 40; c++) {
            float4 wv = ((const float4*)(w0 + (size_t)c * 256))[lane];
            acc[c] = x.x * wv.x + x.y * wv.y + x.z * wv.z + x.w * wv.w;
        }
        #pragma unroll
        for (int c = 0; c < 8; c++) {
            float4 wv = ((const float4*)(w1 + (size_t)c * 256))[lane];
            acc[40 + c] = x.x * wv.x + x.y * wv.y + x.z * wv.z + x.w * wv.w;
        }
        #pragma unroll
        for (int c = 0; c < 6; c++) {
            float4 wv = ((const float4*)(w2 + (size_t)c * 256))[lane];
            acc[48 + c] = x.x * wv.x + x.y * wv.y + x.z * wv.z + x.w * wv.w;
        }
        #pragma unroll
        for (int c = 0; c < 54; c++)
            for (int o = 32; o; o >>= 1) acc[c] += __shfl_down(acc[c], o);
        if (lane == 0) {
            int y0 = y[(size_t)r * 3 + 0], y1 = y[(size_t)r * 3 + 1], y2 = y[(size_t)r * 3 + 2];
            float m0v = -1e30f, m1v = -1e30f, m2v = -1e30f;
            float t0 = 0.f, t1v = 0.f, t2v = 0.f;
            #pragma unroll
            for (int c = 0; c < 40; c++) {
                float v = acc[c] + b0[c];
                acc[c] = v; m0v = fmaxf(m0v, v);
                if (c == y0) t0 = v;
            }
            #pragma unroll
            for (int c = 0; c < 8; c++) {
                float v = acc[40 + c] + b1[c];
                acc[40 + c] = v; m1v = fmaxf(m1v, v);
                if (c == y1) t1v = v;
            }
            #pragma unroll
            for (int c = 0; c < 6; c++) {
                float v = acc[48 + c] + b2[c];
                acc[48 + c] = v; m2v = fmaxf(m2v, v);
                if (c == y2) t2v = v;
            }
            float s0 = 0.f, s1 = 0.f, s2 = 0.f;
            #pragma unroll
            for (int c = 0; c < 40; c++) s0 += __expf(acc[c] - m0v);
            #pragma unroll
            for (int c = 0; c < 8; c++)  s1 += __expf(acc[40 + c] - m1v);
            #pragma unroll
            for (int c = 0; c < 6; c++)  s2 += __expf(acc[48 + c] - m2v);
            local += (m0v + logf(s0) - t0) + (m1v + logf(s1) - t1v) + (m2v + logf(s2) - t2v);
        }
    }
    __shared__ float ls[4];
    if (lane == 0) ls[wave] = local;
    __syncthreads();
    if (threadIdx.x == 0)
        atomicAdd(lossOut, (ls[0] + ls[1] + ls[2] + ls[3]) * invM);
}

// ---------------- host ----------------

extern "C" void kernel_launch(void* const* d_in, const int* in_sizes, int n_in,
                              void* d_out, int out_size, void* d_ws, size_t ws_size,
                              hipStream_t stream)
{
    (void)in_sizes; (void)n_in; (void)out_size; (void)ws_size;
    const float* zin      = (const float*)d_in[0];
    const int*   atom_i   = (const int*)d_in[1];
    const float* atom_x   = (const float*)d_in[2];
    const int*   atom_y   = (const int*)d_in[3];
    const int*   bond_y   = (const int*)d_in[4];
    const float* Wp       = (const float*)d_in[5];
    const float* bp       = (const float*)d_in[6];
    const float* bn_g     = (const float*)d_in[7];
    const float* bn_b     = (const float*)d_in[8];
    const float* nd_qkv_w = (const float*)d_in[9];
    const float* nd_qkv_b = (const float*)d_in[10];
    const float* nd_so_w  = (const float*)d_in[11];
    const float* nd_so_b  = (const float*)d_in[12];
    const float* nd_cqkv_w= (const float*)d_in[13];
    const float* nd_cqkv_b= (const float*)d_in[14];
    const float* nd_co_w  = (const float*)d_in[15];
    const float* nd_co_b  = (const float*)d_in[16];
    const float* nd_ff1_w = (const float*)d_in[17];
    const float* nd_ff1_b = (const float*)d_in[18];
    const float* nd_ff2_w = (const float*)d_in[19];
    const float* nd_ff2_b = (const float*)d_in[20];
    const float* nd_ln_g  = (const float*)d_in[21];
    const float* nd_ln_b  = (const float*)d_in[22];
    const float* nd_fn_g  = (const float*)d_in[23];
    const float* nd_fn_b  = (const float*)d_in[24];
    const float* ed_qkv_w = (const float*)d_in[25];
    const float* ed_qkv_b = (const float*)d_in[26];
    const float* ed_so_w  = (const float*)d_in[27];
    const float* ed_so_b  = (const float*)d_in[28];
    const float* ed_cqkv_w= (const float*)d_in[29];
    const float* ed_cqkv_b= (const float*)d_in[30];
    const float* ed_co_w  = (const float*)d_in[31];
    const float* ed_co_b  = (const float*)d_in[32];
    const float* ed_ff1_w = (const float*)d_in[33];
    const float* ed_ff1_b = (const float*)d_in[34];
    const float* ed_ff2_w = (const float*)d_in[35];
    const float* ed_ff2_b = (const float*)d_in[36];
    const float* ed_ln_g  = (const float*)d_in[37];
    const float* ed_ln_b  = (const float*)d_in[38];
    const float* ed_fn_g  = (const float*)d_in[39];
    const float* ed_fn_b  = (const float*)d_in[40];
    const float* nc0_w = (const float*)d_in[41]; const float* nc0_b = (const float*)d_in[42];
    const float* nc1_w = (const float*)d_in[43]; const float* nc1_b = (const float*)d_in[44];
    const float* nc2_w = (const float*)d_in[45]; const float* nc2_b = (const float*)d_in[46];
    const float* ec0_w = (const float*)d_in[47]; const float* ec0_b = (const float*)d_in[48];
    const float* ec1_w = (const float*)d_in[49]; const float* ec1_b = (const float*)d_in[50];

    float* out = (float*)d_out;

    char* wsb = (char*)d_ws;
    size_t off = 0;
    auto alloc = [&](size_t nbytes) -> void* {
        void* p = (void*)(wsb + off);
        off += (nbytes + 255) / 256 * 256;
        return p;
    };
    float* x0    = (float*)alloc(1024 * 256 * 4);
    float* tgt   = (float*)alloc(1024 * 256 * 4);
    float* nqkv  = (float*)alloc(1024 * 768 * 4);
    float* t1    = (float*)alloc(1024 * 256 * 4);
    float* nemb  = (float*)alloc(1024 * 256 * 4);
    float* bnsums= (float*)alloc(512 * 4);
    float* crO   = (float*)alloc(2 * 1024 * 4);
    float* memb  = (float*)alloc(1028 * 256 * 4);
    float* KV    = (float*)alloc(1028 * 512 * 4);
    float* Vt    = (float*)alloc(8 * 32768 * 4);
    float* etgt  = (float*)alloc((size_t)LEB * 256 * 4);
    float* et1   = (float*)alloc((size_t)LEB * 256 * 4);
    int* grp   = (int*)alloc(LE * 4);
    int* idxt  = (int*)alloc(LE * 4);
    ushort* wpk = (ushort*)alloc((size_t)TOTFRAG * 512 * 2);

    PackArgs pa;
    pa.src[0] = nd_qkv_w;              pa.src[1] = nd_qkv_w + 768 * 256;
    pa.src[2] = nd_so_w;               pa.src[3] = nd_so_w + 65536;
    pa.src[4] = nd_ff1_w;              pa.src[5] = nd_ff1_w + 65536;
    pa.src[6] = nd_ff2_w;              pa.src[7] = nd_ff2_w + 65536;
    pa.src[8] = ed_qkv_w;              pa.src[9] = ed_cqkv_w;
    pa.src[10] = ed_so_w;              pa.src[11] = ed_co_w;
    pa.src[12] = ed_ff1_w;             pa.src[13] = ed_ff2_w;
    int fs[NPACK + 1] = {0, 384, 768, 896, 1024, 1152, 1280, 1408, 1536, 1920, 2304, 2432, 2560, 2688, 2816};
    for (int i = 0; i <= NPACK; i++) pa.fs[i] = fs[i];
    auto wp = [&](int i) -> const ushort* { return wpk + (size_t)fs[i] * 512; };

    k_init<<<13, 256, 0, stream>>>(out, bnsums, grp, idxt);
    k_prep<<<(TOTFRAG * 64 + 255) / 256, 256, 0, stream>>>(pa, wpk);

    // node input: projection + BN + SELU + PE
    k_gemm<<<dim3(4, 16), dim3(16, 16), 0, stream>>>(atom_x, Wp, bp, x0, 1024, 256, 54, 0);
    k_bn_part<<<64, 256, 0, stream>>>(x0, bnsums);
    k_bn_selu_pe<<<1024, 256, 0, stream>>>(x0, bnsums, bn_g, bn_b, atom_i, tgt);

    // both layers' cross-attn constant
    k_cross2<<<dim3(4, 2), 256, 0, stream>>>(zin, nd_cqkv_w, nd_cqkv_b, nd_co_w, nd_co_b, crO);

    // node decoder: 2 layers (3 dispatches each)
    for (int l = 0; l < 2; l++) {
        k_gemm_w<<<dim3(3, 8), 256, 0, stream>>>(tgt, wp(l), nd_qkv_b + l * 768,
                                                 nqkv, Vt, 1024, 768, 3, 0);
        k_attn_fused<<<dim3(4, 8), 256, 0, stream>>>(nqkv, Vt, t1);
        k_node_mega<<<64, 256, 0, stream>>>(
            t1, tgt, crO + l * 1024,
            wp(2 + l), nd_so_b + l * 256,
            nd_ln_g + (l * 3 + 0) * 256, nd_ln_b + (l * 3 + 0) * 256,
            nd_ln_g + (l * 3 + 1) * 256, nd_ln_b + (l * 3 + 1) * 256,
            wp(4 + l), nd_ff1_b + l * 256,
            wp(6 + l), nd_ff2_b + l * 256,
            nd_ln_g + (l * 3 + 2) * 256, nd_ln_b + (l * 3 + 2) * 256,
            nd_fn_g, nd_fn_b,
            (l == 0) ? tgt : nemb, 1024, (l == 1) ? 1 : 0);
    }

    // node losses
    k_ce_node<<<128, 256, 0, stream>>>(nemb, nc0_w, nc0_b, nc1_w, nc1_b, nc2_w, nc2_b,
                                       atom_y, 1024, 1.f / 1024.f, out);

    // edge path
    k_gather_mem<<<LEB + 1028, 256, 0, stream>>>(zin, nemb, idxt, etgt, memb);
    k_gemm_w<<<dim3(2, 17), 256, 0, stream>>>(memb, wp(9) + 128 * 512, ed_cqkv_b + 256,
                                              KV, nullptr, 1028, 512, 0, 0);
    k_edge_qkv_attn<<<dim3(255, 4), 256, 0, stream>>>(etgt, wp(8), ed_qkv_b, et1);
    k_edge_mega<<<(LEB + 15) / 16, 256, 0, stream>>>(
        et1, etgt,
        wp(10), ed_so_b, ed_ln_g, ed_ln_b,
        wp(9), ed_cqkv_b, KV, grp,
        wp(11), ed_co_b, ed_ln_g + 256, ed_ln_b + 256,
        wp(12), ed_ff1_b,
        wp(13), ed_ff2_b, ed_ln_g + 512, ed_ln_b + 512,
        ed_fn_g, ed_fn_b,
        bond_y, ec0_w, ec0_b, ec1_w, ec1_b,
        out, 1.f / (float)LEB, LEB);
}

// Round 14
// 451.744 us; speedup vs baseline: 1.1412x; 1.1412x over previous
//
#include <hip/hip_runtime.h>
#include <math.h>

#define SS 256
#define BB 4
#define HH 256
#define LE 2994
#define LEB (LE*BB)
#define SCALE 0.08838834764831845f  // 1/sqrt(128)
#define QSTR 784   // qlds row stride: 784 % 32 == 16 -> 2-way (free) bank aliasing on 4x16 stores

typedef __attribute__((ext_vector_type(8))) short bf16x8;
typedef __attribute__((ext_vector_type(4))) float f32x4;

__device__ inline ushort f2b(float f) {   // fp32 -> bf16 RNE
    unsigned u = __float_as_uint(f);
    u += 0x7FFFu + ((u >> 16) & 1u);
    return (ushort)(u >> 16);
}

__device__ inline float qred(float x) {   // sum across 16 lanes of a quarter-wave (broadcast)
    x += __shfl_xor(x, 1); x += __shfl_xor(x, 2);
    x += __shfl_xor(x, 4); x += __shfl_xor(x, 8);
    return x;
}

// ---------------- init ----------------

__global__ void k_init(float* __restrict__ out, float* __restrict__ bnsums,
                       int* __restrict__ grp, int* __restrict__ idxt) {
    int bid = blockIdx.x, t = threadIdx.x;
    if (bid == 0) {
        if (t == 0) out[0] = 0.f;
        bnsums[t] = 0.f; bnsums[256 + t] = 0.f;
        return;
    }
    int e = (bid - 1) * 256 + t;
    if (e >= LE) return;
    int g, pos;
    if (e < 78) {
        g = (int)((1.0f + sqrtf(8.0f * (float)e + 1.0f)) * 0.5f);
        while (g * (g - 1) / 2 > e) g--;
        while ((g + 1) * g / 2 <= e) g++;
        pos = e - g * (g - 1) / 2;
        idxt[e] = pos;
    } else {
        int r = e - 78;
        g = 13 + r / 12;
        pos = r % 12;
        idxt[e] = g - 12 + pos;
    }
    grp[e] = g;
}

// ---------------- weight pre-pack ----------------

#define NPACK 14
#define TOTFRAG 2816
struct PackArgs { const float* src[NPACK]; int fs[NPACK + 1]; };

__global__ __launch_bounds__(256) void k_prep(PackArgs pa, ushort* __restrict__ dst) {
    int wid = (blockIdx.x * 256 + threadIdx.x) >> 6;
    int lane = threadIdx.x & 63;
    if (wid >= TOTFRAG) return;
    int i = 0;
    while (pa.fs[i + 1] <= wid) i++;
    int f = wid - pa.fs[i];
    int tn = f >> 3, tk = f & 7;
    int q = lane >> 4, p = lane & 15;
    const float* s = pa.src[i] + (size_t)(tn * 16 + p) * 256 + tk * 32 + q * 8;
    float4 a0 = *(const float4*)s, a1 = *(const float4*)(s + 4);
    uint4 o = make_uint4(f2b(a0.x) | ((unsigned)f2b(a0.y) << 16),
                         f2b(a0.z) | ((unsigned)f2b(a0.w) << 16),
                         f2b(a1.x) | ((unsigned)f2b(a1.y) << 16),
                         f2b(a1.z) | ((unsigned)f2b(a1.w) << 16));
    *(uint4*)&dst[(size_t)wid * 512 + lane * 8] = o;
}

// ---------------- plain bf16 GEMM with packed W (modes 0/3), 64-row x 256-col tiles ----------------

__global__ __launch_bounds__(256) void k_gemm_w(
    const float* __restrict__ A, const ushort* __restrict__ Wp,
    const float* __restrict__ bias, float* __restrict__ C, float* __restrict__ Vt,
    int M, int N, int mode, int relu)
{
    __shared__ ushort As[32 * 512];
    int tid = threadIdx.x;
    int w = tid >> 6, lane = tid & 63;
    int q = lane >> 4, p = lane & 15;
    int m0 = blockIdx.y * 64, n0 = blockIdx.x * 256;

    {
        int r = tid >> 2;
        int cbase = (tid & 3) * 64;
        int gm = m0 + r;
        const float* Ar = A + (size_t)gm * 256 + cbase;
        bool ok = gm < M;
        #pragma unroll
        for (int j = 0; j < 8; j++) {
            int c = cbase + j * 8;
            float4 a0, a1;
            if (ok) { a0 = *(const float4*)(Ar + j * 8); a1 = *(const float4*)(Ar + j * 8 + 4); }
            else { a0 = make_float4(0.f, 0.f, 0.f, 0.f); a1 = a0; }
            uint4 o = make_uint4(f2b(a0.x) | ((unsigned)f2b(a0.y) << 16),
                                 f2b(a0.z) | ((unsigned)f2b(a0.w) << 16),
                                 f2b(a1.x) | ((unsigned)f2b(a1.y) << 16),
                                 f2b(a1.z) | ((unsigned)f2b(a1.w) << 16));
            int frag = (r >> 4) * 8 + (c >> 5);
            int fl = ((c >> 3) & 3) * 16 + (r & 15);
            *(uint4*)&As[frag * 512 + fl * 8] = o;
        }
    }
    __syncthreads();

    f32x4 acc[4][4];
    #pragma unroll
    for (int i = 0; i < 4; i++)
        #pragma unroll
        for (int j = 0; j < 4; j++) acc[i][j] = (f32x4){0.f, 0.f, 0.f, 0.f};

    int nw = n0 + w * 64;
    const ushort* Wb = Wp + (size_t)(nw >> 4) * 4096;

    #pragma unroll
    for (int kt = 0; kt < 8; kt++) {
        bf16x8 afr[4], wfr[4];
        #pragma unroll
        for (int mt = 0; mt < 4; mt++)
            afr[mt] = *(const bf16x8*)&As[(mt * 8 + kt) * 512 + lane * 8];
        #pragma unroll
        for (int nt = 0; nt < 4; nt++)
            wfr[nt] = *(const bf16x8*)&Wb[(size_t)(nt * 8 + kt) * 512 + lane * 8];
        #pragma unroll
        for (int mt = 0; mt < 4; mt++)
            #pragma unroll
            for (int nt = 0; nt < 4; nt++)
                acc[mt][nt] = __builtin_amdgcn_mfma_f32_16x16x32_bf16(afr[mt], wfr[nt], acc[mt][nt], 0, 0, 0);
    }

    float bi[4]; int col[4];
    #pragma unroll
    for (int nt = 0; nt < 4; nt++) { col[nt] = nw + nt * 16 + p; bi[nt] = bias[col[nt]]; }
    #pragma unroll
    for (int mt = 0; mt < 4; mt++)
        #pragma unroll
        for (int reg = 0; reg < 4; reg++) {
            int grow = m0 + mt * 16 + q * 4 + reg;
            if (grow >= M) continue;
            #pragma unroll
            for (int nt = 0; nt < 4; nt++) {
                float v = acc[mt][nt][reg] + bi[nt];
                if (relu) v = fmaxf(v, 0.f);
                if (mode == 3) {
                    if (col[nt] < 512) {
                        C[(size_t)grow * 768 + col[nt]] = v;
                    } else {
                        int hh = (col[nt] - 512) >> 7, dh = (col[nt] - 512) & 127;
                        int zz = (grow & 3) * 2 + hh;
                        Vt[(size_t)zz * 32768 + (size_t)dh * 256 + (grow >> 2)] = v;
                    }
                } else {
                    C[(size_t)grow * N + col[nt]] = v;
                }
            }
        }
}

// ---------------- 16-row / 4-wave pipeline building blocks ----------------

__device__ inline void stageA_16(const float* __restrict__ A, int M, int m0, int tid,
                                 ushort* __restrict__ As) {
    int r = tid >> 4;
    int cbase = (tid & 15) * 16;
    int gm = m0 + r;
    const float* Ar = A + (size_t)gm * 256 + cbase;
    bool ok = gm < M;
    #pragma unroll
    for (int j = 0; j < 2; j++) {
        int c = cbase + j * 8;
        float4 a0, a1;
        if (ok) { a0 = *(const float4*)(Ar + j * 8); a1 = *(const float4*)(Ar + j * 8 + 4); }
        else { a0 = make_float4(0.f, 0.f, 0.f, 0.f); a1 = a0; }
        uint4 o = make_uint4(f2b(a0.x) | ((unsigned)f2b(a0.y) << 16),
                             f2b(a0.z) | ((unsigned)f2b(a0.w) << 16),
                             f2b(a1.x) | ((unsigned)f2b(a1.y) << 16),
                             f2b(a1.z) | ((unsigned)f2b(a1.w) << 16));
        int frag = c >> 5;
        int fl = ((c >> 3) & 3) * 16 + r;
        *(uint4*)&As[frag * 512 + fl * 8] = o;
    }
    __syncthreads();
}

__device__ inline void gemm_pass16(const ushort* __restrict__ As, const ushort* __restrict__ Wq,
                                   int w, int lane, f32x4 (&acc)[4]) {
    #pragma unroll
    for (int nt = 0; nt < 4; nt++) acc[nt] = (f32x4){0.f, 0.f, 0.f, 0.f};
    #pragma unroll
    for (int kt = 0; kt < 8; kt++) {
        bf16x8 a0 = *(const bf16x8*)&As[kt * 512 + lane * 8];
        #pragma unroll
        for (int nt = 0; nt < 4; nt++) {
            bf16x8 wf = *(const bf16x8*)&Wq[(size_t)((w * 4 + nt) * 8 + kt) * 512 + lane * 8];
            acc[nt] = __builtin_amdgcn_mfma_f32_16x16x32_bf16(a0, wf, acc[nt], 0, 0, 0);
        }
    }
}

__device__ inline void stage_acc16(const f32x4 (&acc)[4], ushort* __restrict__ As,
                                   int w, int q, int p) {
    __syncthreads();
    #pragma unroll
    for (int nt = 0; nt < 4; nt++)
        #pragma unroll
        for (int reg = 0; reg < 4; reg++)
            As[(w * 2 + (nt >> 1)) * 512 +
               (((nt * 2 + (p >> 3)) & 3) * 16 + q * 4 + reg) * 8 + (p & 7)] =
                f2b(acc[nt][reg]);
    __syncthreads();
}

__device__ inline void block_ln16(f32x4 (&acc)[4], float* __restrict__ red,
                                  int tid, int w, int q, int p,
                                  const float* __restrict__ g, const float* __restrict__ b) {
    float gg[4], bb[4];
    #pragma unroll
    for (int nt = 0; nt < 4; nt++) { int col = w * 64 + nt * 16 + p; gg[nt] = g[col]; bb[nt] = b[col]; }
    #pragma unroll
    for (int reg = 0; reg < 4; reg++) {
        float s = acc[0][reg] + acc[1][reg] + acc[2][reg] + acc[3][reg];
        s = qred(s);
        if (p == 0) red[w * 16 + q * 4 + reg] = s;
    }
    __syncthreads();
    if (tid < 16) red[64 + tid] = (red[tid] + red[16 + tid] + red[32 + tid] + red[48 + tid]) * (1.f / 256.f);
    __syncthreads();
    #pragma unroll
    for (int reg = 0; reg < 4; reg++) {
        int lr = q * 4 + reg;
        float mean = red[64 + lr];
        float sq = 0.f;
        #pragma unroll
        for (int nt = 0; nt < 4; nt++) {
            acc[nt][reg] -= mean;
            sq += acc[nt][reg] * acc[nt][reg];
        }
        sq = qred(sq);
        if (p == 0) red[w * 16 + lr] = sq;
    }
    __syncthreads();
    if (tid < 16) red[64 + tid] = rsqrtf((red[tid] + red[16 + tid] + red[32 + tid] + red[48 + tid]) * (1.f / 256.f) + 1e-5f);
    __syncthreads();
    #pragma unroll
    for (int reg = 0; reg < 4; reg++) {
        float rstd = red[64 + q * 4 + reg];
        #pragma unroll
        for (int nt = 0; nt < 4; nt++)
            acc[nt][reg] = acc[nt][reg] * rstd * gg[nt] + bb[nt];
    }
    __syncthreads();
}

// ---------------- node mega: so+LN, +crO+LN, ff1, ff2+LN(+final LN) — 16 rows/block ----------------

__global__ __launch_bounds__(256) void k_node_mega(
    const float* __restrict__ t1, const float* __restrict__ tgt,
    const float* __restrict__ crO,
    const ushort* __restrict__ Wso, const float* __restrict__ so_b,
    const float* __restrict__ ln0g, const float* __restrict__ ln0b,
    const float* __restrict__ ln1g, const float* __restrict__ ln1b,
    const ushort* __restrict__ Wff1, const float* __restrict__ ff1_b,
    const ushort* __restrict__ Wff2, const float* __restrict__ ff2_b,
    const float* __restrict__ ln2g, const float* __restrict__ ln2b,
    const float* __restrict__ fng, const float* __restrict__ fnb,
    float* __restrict__ outp, int M, int finalln)
{
    __shared__ ushort As[8 * 512];
    __shared__ float red[128];
    int tid = threadIdx.x;
    int w = tid >> 6, lane = tid & 63, q = lane >> 4, p = lane & 15;
    int m0 = blockIdx.x * 16;

    float x[4][4];
    f32x4 acc[4];

    stageA_16(t1, M, m0, tid, As);
    #pragma unroll
    for (int reg = 0; reg < 4; reg++) {
        int row = m0 + q * 4 + reg;
        bool ok = row < M;
        #pragma unroll
        for (int nt = 0; nt < 4; nt++)
            x[nt][reg] = ok ? tgt[(size_t)row * 256 + w * 64 + nt * 16 + p] : 0.f;
    }

    gemm_pass16(As, Wso, w, lane, acc);
    {
        float bi[4];
        #pragma unroll
        for (int nt = 0; nt < 4; nt++) bi[nt] = so_b[w * 64 + nt * 16 + p];
        #pragma unroll
        for (int nt = 0; nt < 4; nt++)
            #pragma unroll
            for (int reg = 0; reg < 4; reg++)
                acc[nt][reg] += bi[nt] + x[nt][reg];
    }
    block_ln16(acc, red, tid, w, q, p, ln0g, ln0b);

    #pragma unroll
    for (int reg = 0; reg < 4; reg++) {
        int row = m0 + q * 4 + reg;
        int b = row & 3;
        #pragma unroll
        for (int nt = 0; nt < 4; nt++)
            acc[nt][reg] += crO[b * 256 + w * 64 + nt * 16 + p];
    }
    block_ln16(acc, red, tid, w, q, p, ln1g, ln1b);

    #pragma unroll
    for (int nt = 0; nt < 4; nt++)
        #pragma unroll
        for (int reg = 0; reg < 4; reg++)
            x[nt][reg] = acc[nt][reg];

    stage_acc16(acc, As, w, q, p);
    gemm_pass16(As, Wff1, w, lane, acc);
    {
        float bi[4];
        #pragma unroll
        for (int nt = 0; nt < 4; nt++) bi[nt] = ff1_b[w * 64 + nt * 16 + p];
        #pragma unroll
        for (int nt = 0; nt < 4; nt++)
            #pragma unroll
            for (int reg = 0; reg < 4; reg++)
                acc[nt][reg] = fmaxf(acc[nt][reg] + bi[nt], 0.f);
    }

    stage_acc16(acc, As, w, q, p);
    gemm_pass16(As, Wff2, w, lane, acc);
    {
        float bi[4];
        #pragma unroll
        for (int nt = 0; nt < 4; nt++) bi[nt] = ff2_b[w * 64 + nt * 16 + p];
        #pragma unroll
        for (int nt = 0; nt < 4; nt++)
            #pragma unroll
            for (int reg = 0; reg < 4; reg++)
                acc[nt][reg] += bi[nt] + x[nt][reg];
    }
    block_ln16(acc, red, tid, w, q, p, ln2g, ln2b);
    if (finalln) block_ln16(acc, red, tid, w, q, p, fng, fnb);

    #pragma unroll
    for (int reg = 0; reg < 4; reg++) {
        int row = m0 + q * 4 + reg;
        if (row >= M) continue;
        #pragma unroll
        for (int nt = 0; nt < 4; nt++)
            outp[(size_t)row * 256 + w * 64 + nt * 16 + p] = acc[nt][reg];
    }
}

// ---------------- edge mega (16 rows/block) ----------------

__global__ __launch_bounds__(256) void k_edge_mega(
    const float* __restrict__ et1, const float* __restrict__ etgt,
    const ushort* __restrict__ Wso, const float* __restrict__ so_b,
    const float* __restrict__ ln0g, const float* __restrict__ ln0b,
    const ushort* __restrict__ Wcq, const float* __restrict__ cq_b,
    const float* __restrict__ KV, const int* __restrict__ grp,
    const ushort* __restrict__ Wco, const float* __restrict__ co_b,
    const float* __restrict__ ln1g, const float* __restrict__ ln1b,
    const ushort* __restrict__ Wff1, const float* __restrict__ ff1_b,
    const ushort* __restrict__ Wff2, const float* __restrict__ ff2_b,
    const float* __restrict__ ln2g, const float* __restrict__ ln2b,
    const float* __restrict__ fng, const float* __restrict__ fnb,
    const int* __restrict__ ydata,
    const float* __restrict__ cw0, const float* __restrict__ cb0,
    const float* __restrict__ cw1, const float* __restrict__ cb1,
    float* __restrict__ lossOut, float invM, int M)
{
    __shared__ ushort As[8 * 512];
    __shared__ float red[640];
    int tid = threadIdx.x;
    int w = tid >> 6, lane = tid & 63, q = lane >> 4, p = lane & 15;
    int m0 = blockIdx.x * 16;

    float x[4][4];
    f32x4 acc[4];

    stageA_16(et1, M, m0, tid, As);
    #pragma unroll
    for (int reg = 0; reg < 4; reg++) {
        int row = m0 + q * 4 + reg;
        bool ok = row < M;
        #pragma unroll
        for (int nt = 0; nt < 4; nt++)
            x[nt][reg] = ok ? etgt[(size_t)row * 256 + w * 64 + nt * 16 + p] : 0.f;
    }

    gemm_pass16(As, Wso, w, lane, acc);
    {
        float bi[4];
        #pragma unroll
        for (int nt = 0; nt < 4; nt++) bi[nt] = so_b[w * 64 + nt * 16 + p];
        #pragma unroll
        for (int nt = 0; nt < 4; nt++)
            #pragma unroll
            for (int reg = 0; reg < 4; reg++)
                acc[nt][reg] += bi[nt] + x[nt][reg];
    }
    block_ln16(acc, red, tid, w, q, p, ln0g, ln0b);
    #pragma unroll
    for (int nt = 0; nt < 4; nt++)
        #pragma unroll
        for (int reg = 0; reg < 4; reg++)
            x[nt][reg] = acc[nt][reg];

    stage_acc16(acc, As, w, q, p);
    gemm_pass16(As, Wcq, w, lane, acc);
    {
        int h = w >> 1;
        float bi[4];
        #pragma unroll
        for (int nt = 0; nt < 4; nt++) bi[nt] = cq_b[w * 64 + nt * 16 + p];
        #pragma unroll
        for (int reg = 0; reg < 4; reg++) {
            int lr = q * 4 + reg;
            int row = m0 + lr;
            bool ok = row < M;
            int b = row & 3;
            int g = ok ? grp[row >> 2] : 0;
            const float* K0 = KV + (size_t)b * 512 + h * 128;
            const float* K1 = KV + ((size_t)(g + 1) * 4 + b) * 512 + h * 128;
            float s0 = 0.f, s1 = 0.f;
            #pragma unroll
            for (int nt = 0; nt < 4; nt++) {
                float qv = acc[nt][reg] + bi[nt];
                int d = (w & 1) * 64 + nt * 16 + p;
                s0 += qv * K0[d]; s1 += qv * K1[d];
            }
            s0 = qred(s0); s1 = qred(s1);
            if (p == 0) { red[(w * 16 + lr) * 2 + 0] = s0; red[(w * 16 + lr) * 2 + 1] = s1; }
        }
        __syncthreads();
        if (tid < 32) {
            int hh = tid >> 4, lr = tid & 15;
            float p0 = (red[((hh * 2) * 16 + lr) * 2 + 0] + red[((hh * 2 + 1) * 16 + lr) * 2 + 0]) * SCALE;
            float p1 = (red[((hh * 2) * 16 + lr) * 2 + 1] + red[((hh * 2 + 1) * 16 + lr) * 2 + 1]) * SCALE;
            float mx = fmaxf(p0, p1);
            float e0 = __expf(p0 - mx), e1 = __expf(p1 - mx);
            float inv = 1.f / (e0 + e1);
            red[128 + (hh * 16 + lr) * 2 + 0] = e0 * inv;
            red[128 + (hh * 16 + lr) * 2 + 1] = e1 * inv;
        }
        __syncthreads();
        #pragma unroll
        for (int reg = 0; reg < 4; reg++) {
            int lr = q * 4 + reg;
            int row = m0 + lr;
            bool ok = row < M;
            int b = row & 3;
            int g = ok ? grp[row >> 2] : 0;
            float e0 = red[128 + (h * 16 + lr) * 2 + 0];
            float e1 = red[128 + (h * 16 + lr) * 2 + 1];
            const float* V0 = KV + (size_t)b * 512 + 256 + h * 128;
            const float* V1 = KV + ((size_t)(g + 1) * 4 + b) * 512 + 256 + h * 128;
            #pragma unroll
            for (int nt = 0; nt < 4; nt++) {
                int d = (w & 1) * 64 + nt * 16 + p;
                acc[nt][reg] = e0 * V0[d] + e1 * V1[d];
            }
        }
        __syncthreads();
    }

    stage_acc16(acc, As, w, q, p);
    gemm_pass16(As, Wco, w, lane, acc);
    {
        float bi[4];
        #pragma unroll
        for (int nt = 0; nt < 4; nt++) bi[nt] = co_b[w * 64 + nt * 16 + p];
        #pragma unroll
        for (int nt = 0; nt < 4; nt++)
            #pragma unroll
            for (int reg = 0; reg < 4; reg++)
                acc[nt][reg] += bi[nt] + x[nt][reg];
    }
    block_ln16(acc, red, tid, w, q, p, ln1g, ln1b);
    #pragma unroll
    for (int nt = 0; nt < 4; nt++)
        #pragma unroll
        for (int reg = 0; reg < 4; reg++)
            x[nt][reg] = acc[nt][reg];

    stage_acc16(acc, As, w, q, p);
    gemm_pass16(As, Wff1, w, lane, acc);
    {
        float bi[4];
        #pragma unroll
        for (int nt = 0; nt < 4; nt++) bi[nt] = ff1_b[w * 64 + nt * 16 + p];
        #pragma unroll
        for (int nt = 0; nt < 4; nt++)
            #pragma unroll
            for (int reg = 0; reg < 4; reg++)
                acc[nt][reg] = fmaxf(acc[nt][reg] + bi[nt], 0.f);
    }

    stage_acc16(acc, As, w, q, p);
    gemm_pass16(As, Wff2, w, lane, acc);
    {
        float bi[4];
        #pragma unroll
        for (int nt = 0; nt < 4; nt++) bi[nt] = ff2_b[w * 64 + nt * 16 + p];
        #pragma unroll
        for (int nt = 0; nt < 4; nt++)
            #pragma unroll
            for (int reg = 0; reg < 4; reg++)
                acc[nt][reg] += bi[nt] + x[nt][reg];
    }
    block_ln16(acc, red, tid, w, q, p, ln2g, ln2b);
    block_ln16(acc, red, tid, w, q, p, fng, fnb);

    #pragma unroll
    for (int c = 0; c < 9; c++) {
        const float* wc = (c < 5) ? (cw0 + (size_t)c * 256) : (cw1 + (size_t)(c - 5) * 256);
        float wv[4];
        #pragma unroll
        for (int nt = 0; nt < 4; nt++) wv[nt] = wc[w * 64 + nt * 16 + p];
        #pragma unroll
        for (int reg = 0; reg < 4; reg++) {
            float s = acc[0][reg] * wv[0] + acc[1][reg] * wv[1]
                    + acc[2][reg] * wv[2] + acc[3][reg] * wv[3];
            s = qred(s);
            if (p == 0) red[(c * 4 + w) * 16 + q * 4 + reg] = s;
        }
    }
    __syncthreads();
    if (tid < 16) {
        float local = 0.f;
        int grow = m0 + tid;
        if (grow < M) {
            int y0 = ydata[(size_t)grow * 2 + 0], y1 = ydata[(size_t)grow * 2 + 1];
            float lg[9];
            #pragma unroll
            for (int c = 0; c < 9; c++)
                lg[c] = red[(c * 4 + 0) * 16 + tid] + red[(c * 4 + 1) * 16 + tid]
                      + red[(c * 4 + 2) * 16 + tid] + red[(c * 4 + 3) * 16 + tid]
                      + ((c < 5) ? cb0[c] : cb1[c - 5]);
            float mA = -1e30f, mB = -1e30f, tA = 0.f, tB = 0.f;
            #pragma unroll
            for (int c = 0; c < 5; c++) { mA = fmaxf(mA, lg[c]); if (c == y0) tA = lg[c]; }
            #pragma unroll
            for (int c = 0; c < 4; c++) { mB = fmaxf(mB, lg[5 + c]); if (c == y1) tB = lg[5 + c]; }
            float sA = 0.f, sB = 0.f;
            #pragma unroll
            for (int c = 0; c < 5; c++) sA += __expf(lg[c] - mA);
            #pragma unroll
            for (int c = 0; c < 4; c++) sB += __expf(lg[5 + c] - mB);
            local = (mA + logf(sA) - tA) + (mB + logf(sB) - tB);
        }
        for (int o = 8; o; o >>= 1) local += __shfl_down(local, o);
        if (tid == 0) atomicAdd(lossOut, local * invM);
    }
}

// ---------------- fused node attention: QK^T + softmax + PV in one kernel ----------------

__global__ __launch_bounds__(256) void k_attn_fused(
    const float* __restrict__ qkv, const float* __restrict__ Vt,
    float* __restrict__ outp)
{
    __shared__ ushort Qs[64 * 32];
    __shared__ ushort Ks[256 * 32];
    __shared__ ushort Pl[32 * 512];
    int tid = threadIdx.x;
    int wave = tid >> 6, lane = tid & 63;
    int q = lane >> 4, p = lane & 15;
    int m0 = blockIdx.x * 64;
    int z = blockIdx.y, b = z >> 1, h = z & 1;
    size_t qoff = (size_t)b * 768 + h * 128;

    f32x4 acc[16];
    #pragma unroll
    for (int i = 0; i < 16; i++) acc[i] = (f32x4){0.f, 0.f, 0.f, 0.f};

    int sra = tid >> 2, sca = (tid & 3) << 3;
    const float* Arow = qkv + (size_t)(m0 + sra) * 3072 + qoff + sca;
    const float* Wrow = qkv + (size_t)tid * 3072 + qoff + 256;
    ushort* asd = &Qs[sra * 32 + sca];
    ushort* wsd = &Ks[tid * 32];

    for (int k0 = 0; k0 < 128; k0 += 32) {
        float4 a0 = *(const float4*)(Arow + k0);
        float4 a1 = *(const float4*)(Arow + k0 + 4);
        float av[8] = {a0.x, a0.y, a0.z, a0.w, a1.x, a1.y, a1.z, a1.w};
        float wv[32];
        #pragma unroll
        for (int i = 0; i < 8; i++) {
            float4 w4 = *(const float4*)(Wrow + k0 + i * 4);
            wv[i*4+0] = w4.x; wv[i*4+1] = w4.y; wv[i*4+2] = w4.z; wv[i*4+3] = w4.w;
        }
        unsigned au[4], wu[16];
        #pragma unroll
        for (int i = 0; i < 4; i++) au[i] = (unsigned)f2b(av[2*i]) | ((unsigned)f2b(av[2*i+1]) << 16);
        #pragma unroll
        for (int i = 0; i < 16; i++) wu[i] = (unsigned)f2b(wv[2*i]) | ((unsigned)f2b(wv[2*i+1]) << 16);
        __syncthreads();
        ((uint4*)asd)[0] = make_uint4(au[0], au[1], au[2], au[3]);
        ((uint4*)wsd)[0] = make_uint4(wu[0], wu[1], wu[2], wu[3]);
        ((uint4*)(wsd + 8))[0] = make_uint4(wu[4], wu[5], wu[6], wu[7]);
        ((uint4*)(wsd + 16))[0] = make_uint4(wu[8], wu[9], wu[10], wu[11]);
        ((uint4*)(wsd + 24))[0] = make_uint4(wu[12], wu[13], wu[14], wu[15]);
        __syncthreads();

        bf16x8 af = *(const bf16x8*)&Qs[(wave * 16 + p) * 32 + q * 8];
        #pragma unroll
        for (int nt = 0; nt < 16; nt++) {
            bf16x8 bf = *(const bf16x8*)&Ks[(nt * 16 + p) * 32 + q * 8];
            acc[nt] = __builtin_amdgcn_mfma_f32_16x16x32_bf16(af, bf, acc[nt], 0, 0, 0);
        }
    }

    #pragma unroll
    for (int reg = 0; reg < 4; reg++) {
        int row = m0 + wave * 16 + q * 4 + reg;
        float v[16]; float mx = -1e30f;
        #pragma unroll
        for (int nt = 0; nt < 16; nt++) {
            int colk = nt * 16 + p;
            float val = (colk <= row) ? acc[nt][reg] * SCALE : -1e30f;
            v[nt] = val; mx = fmaxf(mx, val);
        }
        mx = fmaxf(mx, __shfl_xor(mx, 1)); mx = fmaxf(mx, __shfl_xor(mx, 2));
        mx = fmaxf(mx, __shfl_xor(mx, 4)); mx = fmaxf(mx, __shfl_xor(mx, 8));
        float s = 0.f;
        #pragma unroll
        for (int nt = 0; nt < 16; nt++) {
            int colk = nt * 16 + p;
            float e = (colk <= row) ? __expf(v[nt] - mx) : 0.f;
            v[nt] = e; s += e;
        }
        s += __shfl_xor(s, 1); s += __shfl_xor(s, 2); s += __shfl_xor(s, 4); s += __shfl_xor(s, 8);
        float inv = 1.f / s;
        #pragma unroll
        for (int nt = 0; nt < 16; nt++)
            Pl[(wave * 8 + (nt >> 1)) * 512 +
               ((((nt * 2) + (p >> 3)) & 3) * 16 + q * 4 + reg) * 8 + (p & 7)] = f2b(v[nt] * inv);
    }

    f32x4 a2[8];
    #pragma unroll
    for (int i = 0; i < 8; i++) a2[i] = (f32x4){0.f, 0.f, 0.f, 0.f};
    #pragma unroll
    for (int kt = 0; kt < 8; kt++) {
        bf16x8 af = *(const bf16x8*)&Pl[(wave * 8 + kt) * 512 + lane * 8];
        #pragma unroll
        for (int nt = 0; nt < 8; nt++) {
            const float* vr = Vt + (size_t)z * 32768 + (size_t)(nt * 16 + p) * 256 + kt * 32 + q * 8;
            float4 v0 = *(const float4*)vr;
            float4 v1 = *(const float4*)(vr + 4);
            uint4 wu = make_uint4(f2b(v0.x) | ((unsigned)f2b(v0.y) << 16),
                                  f2b(v0.z) | ((unsigned)f2b(v0.w) << 16),
                                  f2b(v1.x) | ((unsigned)f2b(v1.y) << 16),
                                  f2b(v1.z) | ((unsigned)f2b(v1.w) << 16));
            bf16x8 bf = *(bf16x8*)&wu;
            a2[nt] = __builtin_amdgcn_mfma_f32_16x16x32_bf16(af, bf, a2[nt], 0, 0, 0);
        }
    }
    #pragma unroll
    for (int reg = 0; reg < 4; reg++) {
        int row = m0 + wave * 16 + q * 4 + reg;
        #pragma unroll
        for (int nt = 0; nt < 8; nt++)
            outp[(size_t)row * 1024 + (size_t)b * 256 + h * 128 + nt * 16 + p] = a2[nt][reg];
    }
}

// ---------------- fused edge QKV + group self-attention (block per (g,b)) ----------------

__global__ __launch_bounds__(256) void k_edge_qkv_attn(
    const float* __restrict__ etgt, const ushort* __restrict__ Wq,
    const float* __restrict__ bias, float* __restrict__ et1)
{
    __shared__ ushort As[8 * 512];
    __shared__ float qlds[12 * QSTR];
    __shared__ float ps[2][12][12];
    int tid = threadIdx.x;
    int w = tid >> 6, lane = tid & 63, q = lane >> 4, p = lane & 15;
    int g = blockIdx.x + 1;
    int b = blockIdx.y;
    int gs = min(g, 12);
    int base = (g <= 13) ? g * (g - 1) / 2 : 78 + (g - 13) * 12;

    {
        int r = tid >> 4;
        int cbase = (tid & 15) * 16;
        bool ok = r < gs;
        const float* Ar = etgt + ((size_t)(base + r) * 4 + b) * 256 + cbase;
        #pragma unroll
        for (int j = 0; j < 2; j++) {
            int c = cbase + j * 8;
            float4 a0, a1;
            if (ok) { a0 = *(const float4*)(Ar + j * 8); a1 = *(const float4*)(Ar + j * 8 + 4); }
            else { a0 = make_float4(0.f, 0.f, 0.f, 0.f); a1 = a0; }
            uint4 o = make_uint4(f2b(a0.x) | ((unsigned)f2b(a0.y) << 16),
                                 f2b(a0.z) | ((unsigned)f2b(a0.w) << 16),
                                 f2b(a1.x) | ((unsigned)f2b(a1.y) << 16),
                                 f2b(a1.z) | ((unsigned)f2b(a1.w) << 16));
            *(uint4*)&As[(c >> 5) * 512 + (((c >> 3) & 3) * 16 + r) * 8] = o;
        }
    }
    __syncthreads();

    f32x4 acc[12];
    #pragma unroll
    for (int j = 0; j < 12; j++) acc[j] = (f32x4){0.f, 0.f, 0.f, 0.f};
    #pragma unroll
    for (int kt = 0; kt < 8; kt++) {
        bf16x8 af = *(const bf16x8*)&As[kt * 512 + lane * 8];
        #pragma unroll
        for (int j = 0; j < 12; j++) {
            bf16x8 wf = *(const bf16x8*)&Wq[(size_t)((w * 12 + j) * 8 + kt) * 512 + lane * 8];
            acc[j] = __builtin_amdgcn_mfma_f32_16x16x32_bf16(af, wf, acc[j], 0, 0, 0);
        }
    }
    #pragma unroll
    for (int j = 0; j < 12; j++) {
        int col = (w * 12 + j) * 16 + p;
        float bi = bias[col];
        #pragma unroll
        for (int reg = 0; reg < 4; reg++) {
            int row = q * 4 + reg;
            if (row < 12) qlds[row * QSTR + col] = acc[j][reg] + bi;
        }
    }
    __syncthreads();

    int h = tid >> 7, t = tid & 127;
    for (int pidx = t; pidx < gs * gs; pidx += 128) {
        int i = pidx / gs, jj = pidx - i * gs;
        const float* qp = &qlds[i * QSTR + h * 128];
        const float* kp = &qlds[jj * QSTR + 256 + h * 128];
        float a = 0.f;
        for (int d = 0; d < 128; d++) a = fmaf(qp[d], kp[d], a);
        ps[h][i][jj] = a * SCALE;
    }
    __syncthreads();
    if (t < gs) {
        float m = -1e30f;
        for (int jj = 0; jj < gs; jj++) m = fmaxf(m, ps[h][t][jj]);
        float e[12]; float s = 0.f;
        for (int jj = 0; jj < gs; jj++) { e[jj] = __expf(ps[h][t][jj] - m); s += e[jj]; }
        float inv = 1.f / s;
        for (int jj = 0; jj < gs; jj++) ps[h][t][jj] = e[jj] * inv;
    }
    __syncthreads();
    for (int i = 0; i < gs; i++) {
        float a = 0.f;
        for (int jj = 0; jj < gs; jj++) a = fmaf(ps[h][i][jj], qlds[jj * QSTR + 512 + h * 128 + t], a);
        et1[((size_t)(base + i) * 4 + b) * 256 + h * 128 + t] = a;
    }
}

// ---------------- generic fp32 GEMM (input projection K=54 only) ----------------

__global__ __launch_bounds__(256) void k_gemm(
    const float* __restrict__ A, const float* __restrict__ W,
    const float* __restrict__ bias, float* __restrict__ C,
    int M, int N, int K, int relu)
{
    __shared__ __align__(16) float As[16][68];
    __shared__ __align__(16) float Ws[16][68];
    int tx = threadIdx.x, ty = threadIdx.y;
    int tid = ty * 16 + tx;
    int m0 = blockIdx.y * 64, n0 = blockIdx.x * 64;
    float acc[4][4] = {{0.f}};
    int r  = tid >> 2;
    int kk = (tid & 3) << 2;
    for (int k0 = 0; k0 < K; k0 += 16) {
        float4 av = make_float4(0.f, 0.f, 0.f, 0.f);
        float4 wv = make_float4(0.f, 0.f, 0.f, 0.f);
        int gm = m0 + r, gk = k0 + kk;
        if (gm < M) {
            float tv[4];
            for (int i = 0; i < 4; i++) tv[i] = (gk + i < K) ? A[(size_t)gm * K + gk + i] : 0.f;
            av = make_float4(tv[0], tv[1], tv[2], tv[3]);
        }
        int gn = n0 + r;
        if (gn < N) {
            float tv[4];
            for (int i = 0; i < 4; i++) tv[i] = (gk + i < K) ? W[(size_t)gn * K + gk + i] : 0.f;
            wv = make_float4(tv[0], tv[1], tv[2], tv[3]);
        }
        As[kk + 0][r] = av.x; As[kk + 1][r] = av.y; As[kk + 2][r] = av.z; As[kk + 3][r] = av.w;
        Ws[kk + 0][r] = wv.x; Ws[kk + 1][r] = wv.y; Ws[kk + 2][r] = wv.z; Ws[kk + 3][r] = wv.w;
        __syncthreads();
        #pragma unroll
        for (int k = 0; k < 16; k++) {
            float4 a4 = *(const float4*)&As[k][ty << 2];
            float4 b4 = *(const float4*)&Ws[k][tx << 2];
            float a[4] = {a4.x, a4.y, a4.z, a4.w};
            float b[4] = {b4.x, b4.y, b4.z, b4.w};
            #pragma unroll
            for (int i = 0; i < 4; i++)
                #pragma unroll
                for (int j = 0; j < 4; j++)
                    acc[i][j] = fmaf(a[i], b[j], acc[i][j]);
        }
        __syncthreads();
    }
    #pragma unroll
    for (int i = 0; i < 4; i++) {
        int gm = m0 + (ty << 2) + i;
        if (gm >= M) continue;
        #pragma unroll
        for (int j = 0; j < 4; j++) {
            int gn = n0 + (tx << 2) + j;
            if (gn >= N) continue;
            float v = acc[i][j] + bias[gn];
            if (relu) v = fmaxf(v, 0.f);
            C[(size_t)gm * N + gn] = v;
        }
    }
}

// ---------------- BatchNorm partial sums ----------------

__global__ __launch_bounds__(256) void k_bn_part(const float* __restrict__ x, float* __restrict__ sums) {
    int t = threadIdx.x;
    int r0 = blockIdx.x * 16;
    float s = 0.f, s2 = 0.f;
    for (int r = r0; r < r0 + 16; r++) {
        float v = x[(size_t)r * 256 + t];
        s += v; s2 += v * v;
    }
    atomicAdd(&sums[t], s);
    atomicAdd(&sums[256 + t], s2);
}

// ---------------- BN-finalize + SELU + positional encoding ----------------

__global__ __launch_bounds__(256) void k_bn_selu_pe(
    const float* __restrict__ x0, const float* __restrict__ sums,
    const float* __restrict__ g, const float* __restrict__ b,
    const int* __restrict__ atom_i, float* __restrict__ out)
{
    int row = blockIdx.x, t = threadIdx.x;
    float m = sums[t] * (1.f / 1024.f);
    float var = sums[256 + t] * (1.f / 1024.f) - m * m;
    float rstd = rsqrtf(var + 1e-5f);
    float v = x0[(size_t)row * 256 + t];
    v = (v - m) * rstd * g[t] + b[t];
    const float SC = 1.0507009873554805f, AL = 1.6732632423543772f;
    v = SC * (v > 0.f ? v : AL * expm1f(v));
    float pos = (float)atom_i[row];
    float freq = expf(-(float)t * (9.210340371976184f / 256.f));
    float ang = pos * freq;
    float pe = (t & 1) ? cosf(ang) : sinf(ang);
    out[(size_t)row * 256 + t] = v + pe;
}

// ---------------- both-layer node cross-attn constant ----------------

__global__ __launch_bounds__(256) void k_cross2(
    const float* __restrict__ z, const float* __restrict__ cqkv_w, const float* __restrict__ cqkv_b,
    const float* __restrict__ co_w, const float* __restrict__ co_b, float* __restrict__ crO)
{
    int m = blockIdx.x, l = blockIdx.y;
    int t = threadIdx.x;
    __shared__ float zs[256], ct[256];
    zs[t] = z[m * 256 + t];
    __syncthreads();
    const float* wv = cqkv_w + (size_t)l * 768 * 256 + 512 * 256 + (size_t)t * 256;
    float a = cqkv_b[l * 768 + 512 + t];
    for (int d = 0; d < 256; d += 4) {
        float4 w4 = *(const float4*)(wv + d);
        a += zs[d] * w4.x + zs[d+1] * w4.y + zs[d+2] * w4.z + zs[d+3] * w4.w;
    }
    ct[t] = a;
    __syncthreads();
    const float* ow = co_w + (size_t)l * 65536 + (size_t)t * 256;
    float o = co_b[l * 256 + t];
    for (int d = 0; d < 256; d += 4) {
        float4 w4 = *(const float4*)(ow + d);
        o += ct[d] * w4.x + ct[d+1] * w4.y + ct[d+2] * w4.z + ct[d+3] * w4.w;
    }
    crO[l * 1024 + m * 256 + t] = o;
}

// ---------------- gather + build_mem fused ----------------

__global__ __launch_bounds__(256) void k_gather_mem(
    const float* __restrict__ z, const float* __restrict__ nemb,
    const int* __restrict__ idxt, float* __restrict__ etgt, float* __restrict__ memb)
{
    int r = blockIdx.x, t = threadIdx.x;
    if (r < LEB) {
        int e = r >> 2, b = r & 3;
        etgt[(size_t)r * 256 + t] = nemb[((size_t)idxt[e] * 4 + b) * 256 + t];
    } else {
        int rm = r - LEB;
        int m = rm >> 2, b = rm & 3;
        memb[(size_t)rm * 256 + t] = (m == 0) ? z[(size_t)b * 256 + t]
                                              : nemb[((size_t)(m - 1) * 4 + b) * 256 + t];
    }
}

// ---------------- fused node cross-entropy ----------------

__global__ __launch_bounds__(256) void k_ce_node(
    const float* __restrict__ emb,
    const float* __restrict__ w0, const float* __restrict__ b0,
    const float* __restrict__ w1, const float* __restrict__ b1,
    const float* __restrict__ w2, const float* __restrict__ b2,
    const int* __restrict__ y, int M, float invM, float* __restrict__ lossOut)
{
    int wave = threadIdx.x >> 6, lane = threadIdx.x & 63;
    int wid = blockIdx.x * 4 + wave;
    float local = 0.f;
    for (int r = wid; r < M; r += gridDim.x * 4) {
        float4 x = ((const float4*)(emb + (size_t)r * 256))[lane];
        float acc[54];
        #pragma unroll
        for (int c = 0; c < 40; c++) {
            float4 wv = ((const float4*)(w0 + (size_t)c * 256))[lane];
            acc[c] = x.x * wv.x + x.y * wv.y + x.z * wv.z + x.w * wv.w;
        }
        #pragma unroll
        for (int c = 0; c < 8; c++) {
            float4 wv = ((const float4*)(w1 + (size_t)c * 256))[lane];
            acc[40 + c] = x.x * wv.x + x.y * wv.y + x.z * wv.z + x.w * wv.w;
        }
        #pragma unroll
        for (int c = 0; c < 6; c++) {
            float4 wv = ((const float4*)(w2 + (size_t)c * 256))[lane];
            acc[48 + c] = x.x * wv.x + x.y * wv.y + x.z * wv.z + x.w * wv.w;
        }
        #pragma unroll
        for (int c = 0; c < 54; c++)
            for (int o = 32; o; o >>= 1) acc[c] += __shfl_down(acc[c], o);
        if (lane == 0) {
            int y0 = y[(size_t)r * 3 + 0], y1 = y[(size_t)r * 3 + 1], y2 = y[(size_t)r * 3 + 2];
            float m0v = -1e30f, m1v = -1e30f, m2v = -1e30f;
            float t0 = 0.f, t1v = 0.f, t2v = 0.f;
            #pragma unroll
            for (int c = 0; c < 40; c++) {
                float v = acc[c] + b0[c];
                acc[c] = v; m0v = fmaxf(m0v, v);
                if (c == y0) t0 = v;
            }
            #pragma unroll
            for (int c = 0; c < 8; c++) {
                float v = acc[40 + c] + b1[c];
                acc[40 + c] = v; m1v = fmaxf(m1v, v);
                if (c == y1) t1v = v;
            }
            #pragma unroll
            for (int c = 0; c < 6; c++) {
                float v = acc[48 + c] + b2[c];
                acc[48 + c] = v; m2v = fmaxf(m2v, v);
                if (c == y2) t2v = v;
            }
            float s0 = 0.f, s1 = 0.f, s2 = 0.f;
            #pragma unroll
            for (int c = 0; c < 40; c++) s0 += __expf(acc[c] - m0v);
            #pragma unroll
            for (int c = 0; c < 8; c++)  s1 += __expf(acc[40 + c] - m1v);
            #pragma unroll
            for (int c = 0; c < 6; c++)  s2 += __expf(acc[48 + c] - m2v);
            local += (m0v + logf(s0) - t0) + (m1v + logf(s1) - t1v) + (m2v + logf(s2) - t2v);
        }
    }
    __shared__ float ls[4];
    if (lane == 0) ls[wave] = local;
    __syncthreads();
    if (threadIdx.x == 0)
        atomicAdd(lossOut, (ls[0] + ls[1] + ls[2] + ls[3]) * invM);
}

// ---------------- host ----------------

extern "C" void kernel_launch(void* const* d_in, const int* in_sizes, int n_in,
                              void* d_out, int out_size, void* d_ws, size_t ws_size,
                              hipStream_t stream)
{
    (void)in_sizes; (void)n_in; (void)out_size; (void)ws_size;
    const float* zin      = (const float*)d_in[0];
    const int*   atom_i   = (const int*)d_in[1];
    const float* atom_x   = (const float*)d_in[2];
    const int*   atom_y   = (const int*)d_in[3];
    const int*   bond_y   = (const int*)d_in[4];
    const float* Wp       = (const float*)d_in[5];
    const float* bp       = (const float*)d_in[6];
    const float* bn_g     = (const float*)d_in[7];
    const float* bn_b     = (const float*)d_in[8];
    const float* nd_qkv_w = (const float*)d_in[9];
    const float* nd_qkv_b = (const float*)d_in[10];
    const float* nd_so_w  = (const float*)d_in[11];
    const float* nd_so_b  = (const float*)d_in[12];
    const float* nd_cqkv_w= (const float*)d_in[13];
    const float* nd_cqkv_b= (const float*)d_in[14];
    const float* nd_co_w  = (const float*)d_in[15];
    const float* nd_co_b  = (const float*)d_in[16];
    const float* nd_ff1_w = (const float*)d_in[17];
    const float* nd_ff1_b = (const float*)d_in[18];
    const float* nd_ff2_w = (const float*)d_in[19];
    const float* nd_ff2_b = (const float*)d_in[20];
    const float* nd_ln_g  = (const float*)d_in[21];
    const float* nd_ln_b  = (const float*)d_in[22];
    const float* nd_fn_g  = (const float*)d_in[23];
    const float* nd_fn_b  = (const float*)d_in[24];
    const float* ed_qkv_w = (const float*)d_in[25];
    const float* ed_qkv_b = (const float*)d_in[26];
    const float* ed_so_w  = (const float*)d_in[27];
    const float* ed_so_b  = (const float*)d_in[28];
    const float* ed_cqkv_w= (const float*)d_in[29];
    const float* ed_cqkv_b= (const float*)d_in[30];
    const float* ed_co_w  = (const float*)d_in[31];
    const float* ed_co_b  = (const float*)d_in[32];
    const float* ed_ff1_w = (const float*)d_in[33];
    const float* ed_ff1_b = (const float*)d_in[34];
    const float* ed_ff2_w = (const float*)d_in[35];
    const float* ed_ff2_b = (const float*)d_in[36];
    const float* ed_ln_g  = (const float*)d_in[37];
    const float* ed_ln_b  = (const float*)d_in[38];
    const float* ed_fn_g  = (const float*)d_in[39];
    const float* ed_fn_b  = (const float*)d_in[40];
    const float* nc0_w = (const float*)d_in[41]; const float* nc0_b = (const float*)d_in[42];
    const float* nc1_w = (const float*)d_in[43]; const float* nc1_b = (const float*)d_in[44];
    const float* nc2_w = (const float*)d_in[45]; const float* nc2_b = (const float*)d_in[46];
    const float* ec0_w = (const float*)d_in[47]; const float* ec0_b = (const float*)d_in[48];
    const float* ec1_w = (const float*)d_in[49]; const float* ec1_b = (const float*)d_in[50];

    float* out = (float*)d_out;

    char* wsb = (char*)d_ws;
    size_t off = 0;
    auto alloc = [&](size_t nbytes) -> void* {
        void* p = (void*)(wsb + off);
        off += (nbytes + 255) / 256 * 256;
        return p;
    };
    float* x0    = (float*)alloc(1024 * 256 * 4);
    float* tgt   = (float*)alloc(1024 * 256 * 4);
    float* nqkv  = (float*)alloc(1024 * 768 * 4);
    float* t1    = (float*)alloc(1024 * 256 * 4);
    float* nemb  = (float*)alloc(1024 * 256 * 4);
    float* bnsums= (float*)alloc(512 * 4);
    float* crO   = (float*)alloc(2 * 1024 * 4);
    float* memb  = (float*)alloc(1028 * 256 * 4);
    float* KV    = (float*)alloc(1028 * 512 * 4);
    float* Vt    = (float*)alloc(8 * 32768 * 4);
    float* etgt  = (float*)alloc((size_t)LEB * 256 * 4);
    float* et1   = (float*)alloc((size_t)LEB * 256 * 4);
    int* grp   = (int*)alloc(LE * 4);
    int* idxt  = (int*)alloc(LE * 4);
    ushort* wpk = (ushort*)alloc((size_t)TOTFRAG * 512 * 2);

    PackArgs pa;
    pa.src[0] = nd_qkv_w;              pa.src[1] = nd_qkv_w + 768 * 256;
    pa.src[2] = nd_so_w;               pa.src[3] = nd_so_w + 65536;
    pa.src[4] = nd_ff1_w;              pa.src[5] = nd_ff1_w + 65536;
    pa.src[6] = nd_ff2_w;              pa.src[7] = nd_ff2_w + 65536;
    pa.src[8] = ed_qkv_w;              pa.src[9] = ed_cqkv_w;
    pa.src[10] = ed_so_w;              pa.src[11] = ed_co_w;
    pa.src[12] = ed_ff1_w;             pa.src[13] = ed_ff2_w;
    int fs[NPACK + 1] = {0, 384, 768, 896, 1024, 1152, 1280, 1408, 1536, 1920, 2304, 2432, 2560, 2688, 2816};
    for (int i = 0; i <= NPACK; i++) pa.fs[i] = fs[i];
    auto wp = [&](int i) -> const ushort* { return wpk + (size_t)fs[i] * 512; };

    k_init<<<13, 256, 0, stream>>>(out, bnsums, grp, idxt);
    k_prep<<<(TOTFRAG * 64 + 255) / 256, 256, 0, stream>>>(pa, wpk);

    // node input: projection + BN + SELU + PE
    k_gemm<<<dim3(4, 16), dim3(16, 16), 0, stream>>>(atom_x, Wp, bp, x0, 1024, 256, 54, 0);
    k_bn_part<<<64, 256, 0, stream>>>(x0, bnsums);
    k_bn_selu_pe<<<1024, 256, 0, stream>>>(x0, bnsums, bn_g, bn_b, atom_i, tgt);

    // both layers' cross-attn constant
    k_cross2<<<dim3(4, 2), 256, 0, stream>>>(zin, nd_cqkv_w, nd_cqkv_b, nd_co_w, nd_co_b, crO);

    // node decoder: 2 layers (3 dispatches each)
    for (int l = 0; l < 2; l++) {
        k_gemm_w<<<dim3(3, 8), 256, 0, stream>>>(tgt, wp(l), nd_qkv_b + l * 768,
                                                 nqkv, Vt, 1024, 768, 3, 0);
        k_attn_fused<<<dim3(4, 8), 256, 0, stream>>>(nqkv, Vt, t1);
        k_node_mega<<<64, 256, 0, stream>>>(
            t1, tgt, crO + l * 1024,
            wp(2 + l), nd_so_b + l * 256,
            nd_ln_g + (l * 3 + 0) * 256, nd_ln_b + (l * 3 + 0) * 256,
            nd_ln_g + (l * 3 + 1) * 256, nd_ln_b + (l * 3 + 1) * 256,
            wp(4 + l), nd_ff1_b + l * 256,
            wp(6 + l), nd_ff2_b + l * 256,
            nd_ln_g + (l * 3 + 2) * 256, nd_ln_b + (l * 3 + 2) * 256,
            nd_fn_g, nd_fn_b,
            (l == 0) ? tgt : nemb, 1024, (l == 1) ? 1 : 0);
    }

    // node losses
    k_ce_node<<<128, 256, 0, stream>>>(nemb, nc0_w, nc0_b, nc1_w, nc1_b, nc2_w, nc2_b,
                                       atom_y, 1024, 1.f / 1024.f, out);

    // edge path
    k_gather_mem<<<LEB + 1028, 256, 0, stream>>>(zin, nemb, idxt, etgt, memb);
    k_gemm_w<<<dim3(2, 17), 256, 0, stream>>>(memb, wp(9) + 128 * 512, ed_cqkv_b + 256,
                                              KV, nullptr, 1028, 512, 0, 0);
    k_edge_qkv_attn<<<dim3(255, 4), 256, 0, stream>>>(etgt, wp(8), ed_qkv_b, et1);
    k_edge_mega<<<(LEB + 15) / 16, 256, 0, stream>>>(
        et1, etgt,
        wp(10), ed_so_b, ed_ln_g, ed_ln_b,
        wp(9), ed_cqkv_b, KV, grp,
        wp(11), ed_co_b, ed_ln_g + 256, ed_ln_b + 256,
        wp(12), ed_ff1_b,
        wp(13), ed_ff2_b, ed_ln_g + 512, ed_ln_b + 512,
        ed_fn_g, ed_fn_b,
        bond_y, ec0_w, ec0_b, ec1_w, ec1_b,
        out, 1.f / (float)LEB, LEB);
}